// Round 5
// baseline (10601.691 us; speedup 1.0000x reference)
//
#include <hip/hip_runtime.h>
#include <cstdint>
#include <cstddef>

#define Bdim 256
#define Ndim 96
#define Edim 1024
#define HDdim 300
#define Ldim 2
#define LHdim 600
#define NCdim 7
#define GDdim 900              // HD*(L+1)
#define ROWS (Bdim*Ndim)       // 24576

typedef unsigned short u16;
typedef float f32x4 __attribute__((ext_vector_type(4)));
typedef short bf16x8 __attribute__((ext_vector_type(8)));

// Identity row-perm constants
#define IDP 0x7FFFFFFF, 1, 30, 0, 0

#define AS_GBL(p) ((const __attribute__((address_space(1))) void*)(p))
#define AS_LDS(p) ((__attribute__((address_space(3))) void*)(p))

__device__ inline u16 f2bf(float x) {
    unsigned int u = __builtin_bit_cast(unsigned int, x);
    unsigned int r = (u + 0x7fffu + ((u >> 16) & 1u)) >> 16;   // RNE
    return (u16)r;
}
__device__ inline float bf2f(u16 h) {
    unsigned int u = ((unsigned int)h) << 16;
    return __builtin_bit_cast(float, u);
}

// ---------------------------------------------------------------------------
// fp32 GEMM (fc1 / GAT V / MLP): C[m,n]=act(sum_k A[rowA(m),k]W[n,k]+b)
// ---------------------------------------------------------------------------
template<int ACT, int ACC>
__global__ __launch_bounds__(256) void gemm_tn(
    const float* __restrict__ A, int lda,
    int pmask, int pmul1, int pshift, int pmul2, int padd,
    const float* __restrict__ W, int ldw,
    float* __restrict__ C, int ldc,
    int M, int Nd, int K,
    const float* __restrict__ bias1,
    const float* __restrict__ bias2,
    const float* __restrict__ aptr)
{
    __shared__ __align__(16) float As[16][68];
    __shared__ __align__(16) float Ws[16][68];
    const int bm = blockIdx.x * 64;
    const int bn = blockIdx.y * 64;
    const int tid = threadIdx.x;
    const int lm  = tid & 63;
    const int lk4 = (tid >> 6) << 2;
    const int tm = (tid >> 4) << 2;
    const int tn = (tid & 15) << 2;
    float acc[4][4] = {{0.f,0.f,0.f,0.f},{0.f,0.f,0.f,0.f},{0.f,0.f,0.f,0.f},{0.f,0.f,0.f,0.f}};
    const int am = bm + lm;
    const int wn = bn + lm;
    const int rowA = (am & pmask) * pmul1 + (am >> pshift) * pmul2 + padd;

    for (int k0 = 0; k0 < K; k0 += 16) {
        float4 av, wv;
        const bool fullk = (k0 + 16 <= K);
        if (fullk) {
            av = (am < M)  ? *(const float4*)(A + (size_t)rowA * lda + k0 + lk4) : make_float4(0.f,0.f,0.f,0.f);
            wv = (wn < Nd) ? *(const float4*)(W + (size_t)wn   * ldw + k0 + lk4) : make_float4(0.f,0.f,0.f,0.f);
        } else {
            float ta[4], tw[4];
            #pragma unroll
            for (int u = 0; u < 4; ++u) {
                int k = k0 + lk4 + u;
                ta[u] = (am < M  && k < K) ? A[(size_t)rowA * lda + k] : 0.f;
                tw[u] = (wn < Nd && k < K) ? W[(size_t)wn   * ldw + k] : 0.f;
            }
            av = make_float4(ta[0],ta[1],ta[2],ta[3]);
            wv = make_float4(tw[0],tw[1],tw[2],tw[3]);
        }
        __syncthreads();
        As[lk4+0][lm] = av.x; As[lk4+1][lm] = av.y; As[lk4+2][lm] = av.z; As[lk4+3][lm] = av.w;
        Ws[lk4+0][lm] = wv.x; Ws[lk4+1][lm] = wv.y; Ws[lk4+2][lm] = wv.z; Ws[lk4+3][lm] = wv.w;
        __syncthreads();
        #pragma unroll
        for (int kk = 0; kk < 16; ++kk) {
            float a0[4], w0[4];
            *(float4*)a0 = *(const float4*)&As[kk][tm];
            *(float4*)w0 = *(const float4*)&Ws[kk][tn];
            #pragma unroll
            for (int i = 0; i < 4; ++i)
                #pragma unroll
                for (int j = 0; j < 4; ++j)
                    acc[i][j] = fmaf(a0[i], w0[j], acc[i][j]);
        }
    }

    const float aval = (ACT == 1) ? *aptr : 0.f;
    #pragma unroll
    for (int i = 0; i < 4; ++i) {
        int m = bm + tm + i;
        if (m >= M) continue;
        #pragma unroll
        for (int j = 0; j < 4; ++j) {
            int n = bn + tn + j;
            if (n >= Nd) continue;
            float v = acc[i][j];
            if (bias1) v += bias1[n];
            if (bias2) v += bias2[n];
            if (ACC)   v += C[(size_t)m * ldc + n];
            if (ACT == 1) v = (v >= 0.f) ? v : aval * v;
            C[(size_t)m * ldc + n] = v;
        }
    }
}

// ---------------------------------------------------------------------------
// bf16x3 split MFMA GEMM with global_load_lds staging (m97 pattern).
// A:(M,K) bf16 hi/lo, M mult of 128; W:(N',K) hi/lo with N' = gridDim.y*128
// (rows beyond Nd must be allocated+zeroed). K mult of 32; lda/ldw mult of 8.
// OUT: 0 -> fp32 C; 1 -> split bf16 (Ch,Cl). ACT: 1 -> prelu(aptr).
// Tile 128x128, BK=32, 4 waves; wave wv stages tile wv (AH,AL,WH,WL).
// ---------------------------------------------------------------------------
template<int OUT, int ACT>
__global__ __launch_bounds__(256) void gemm_mfma3(
    const u16* __restrict__ Ah, const u16* __restrict__ Al, int lda,
    const u16* __restrict__ Wh, const u16* __restrict__ Wl, int ldw,
    float* __restrict__ C, u16* __restrict__ Ch, u16* __restrict__ Cl, int ldc,
    int M, int Nd, int K,
    const float* __restrict__ bias, const float* __restrict__ aptr)
{
    __shared__ __align__(16) u16 tiles[4][4][1024];   // [tile][kseg][row*8]
    const int tid  = threadIdx.x;
    const int bm   = blockIdx.x * 128;
    const int bn   = blockIdx.y * 128;
    const int wv   = tid >> 6;
    const int lane = tid & 63;
    const int wr   = (wv >> 1) * 64;
    const int wc   = (wv & 1) * 64;
    const int l15  = lane & 15;
    const int kseg = lane >> 4;

    // per-wave staging source (uniform within wave)
    const u16* wsrc = (wv == 0) ? Ah + (size_t)bm * lda
                    : (wv == 1) ? Al + (size_t)bm * lda
                    : (wv == 2) ? Wh + (size_t)bn * ldw
                    :             Wl + (size_t)bn * ldw;
    const int wld = (wv < 2) ? lda : ldw;
    u16* wdst = &tiles[wv][0][0];

    f32x4 acc[4][4];
    #pragma unroll
    for (int i = 0; i < 4; ++i)
        #pragma unroll
        for (int j = 0; j < 4; ++j) acc[i][j] = (f32x4){0.f,0.f,0.f,0.f};

    for (int k0 = 0; k0 < K; k0 += 32) {
        // stage 8KB tile: 8 wave-level loads, LDS dest = base + lane*16
        #pragma unroll
        for (int p = 0; p < 8; ++p) {
            const u16* g = wsrc + (size_t)((p & 1) * 64 + lane) * wld + k0 + (p >> 1) * 8;
            __builtin_amdgcn_global_load_lds(AS_GBL(g),
                AS_LDS(wdst + (p >> 1) * 1024 + (p & 1) * 512), 16, 0, 0);
        }
        __syncthreads();   // vmcnt(0) drained by compiler before barrier

        bf16x8 aH[4], aL[4], bH[4], bL[4];
        #pragma unroll
        for (int f = 0; f < 4; ++f) {
            int ar = (wr + f * 16 + l15) * 8;
            int br = (wc + f * 16 + l15) * 8;
            aH[f] = *(const bf16x8*)&tiles[0][kseg][ar];
            aL[f] = *(const bf16x8*)&tiles[1][kseg][ar];
            bH[f] = *(const bf16x8*)&tiles[2][kseg][br];
            bL[f] = *(const bf16x8*)&tiles[3][kseg][br];
        }
        #pragma unroll
        for (int i = 0; i < 4; ++i)
            #pragma unroll
            for (int j = 0; j < 4; ++j)
                acc[i][j] = __builtin_amdgcn_mfma_f32_16x16x32_bf16(aH[i], bH[j], acc[i][j], 0, 0, 0);
        #pragma unroll
        for (int i = 0; i < 4; ++i)
            #pragma unroll
            for (int j = 0; j < 4; ++j)
                acc[i][j] = __builtin_amdgcn_mfma_f32_16x16x32_bf16(aH[i], bL[j], acc[i][j], 0, 0, 0);
        #pragma unroll
        for (int i = 0; i < 4; ++i)
            #pragma unroll
            for (int j = 0; j < 4; ++j)
                acc[i][j] = __builtin_amdgcn_mfma_f32_16x16x32_bf16(aL[i], bH[j], acc[i][j], 0, 0, 0);
        __syncthreads();   // protect tiles before next stage
    }

    const float av = (ACT == 1) ? *aptr : 0.f;
    const int r4 = (lane >> 4) * 4;
    #pragma unroll
    for (int j = 0; j < 4; ++j) {
        int col = bn + wc + j * 16 + l15;
        if (col >= Nd) continue;
        float bv = bias ? bias[col] : 0.f;
        #pragma unroll
        for (int i = 0; i < 4; ++i) {
            #pragma unroll
            for (int rr = 0; rr < 4; ++rr) {
                int row = bm + wr + i * 16 + r4 + rr;
                if (row >= M) continue;
                float v = acc[i][j][rr] + bv;
                if (ACT == 1) v = (v >= 0.f) ? v : av * v;
                if (OUT == 0) {
                    C[(size_t)row * ldc + col] = v;
                } else {
                    u16 h = f2bf(v);
                    Ch[(size_t)row * ldc + col] = h;
                    Cl[(size_t)row * ldc + col] = f2bf(v - bf2f(h));
                }
            }
        }
    }
}

// ---------------------------------------------------------------------------
// split fp32 -> bf16 hi/lo with row perm, col/row zero-pad.
// ---------------------------------------------------------------------------
__global__ __launch_bounds__(256) void split_rows(
    const float* __restrict__ src, int srcld,
    int pmask, int pmul1, int pshift, int pmul2, int padd,
    u16* __restrict__ dstH, u16* __restrict__ dstL, int dstld,
    int wcols, int validK, int validRows)
{
    int r = blockIdx.y;
    int c = blockIdx.x * 256 + threadIdx.x;
    if (c >= wcols) return;
    int sr = (r & pmask) * pmul1 + (r >> pshift) * pmul2 + padd;
    float v = 0.f;
    if (c < validK && r < validRows) v = src[(size_t)sr * srcld + c];
    u16 h = f2bf(v);
    dstH[(size_t)r * dstld + c] = h;
    dstL[(size_t)r * dstld + c] = f2bf(v - bf2f(h));
}

// Whh rows permuted to gate-interleaved order: row' = u*4+g
__global__ __launch_bounds__(256) void whh_perm(const float* __restrict__ src, float* __restrict__ dst)
{
    int r = blockIdx.y;
    int c = blockIdx.x * 256 + threadIdx.x;
    if (c >= LHdim) return;
    int sr = (r & 3) * LHdim + (r >> 2);
    dst[(size_t)r * LHdim + c] = src[(size_t)sr * LHdim + c];
}

// biasP[n'] = b_ih[orig]+b_hh[orig], orig = (n'&3)*600+(n'>>2)
__global__ __launch_bounds__(256) void bias_perm(
    const float* __restrict__ bih, const float* __restrict__ bhh, float* __restrict__ dst)
{
    int n = blockIdx.x * 256 + threadIdx.x;
    if (n >= 4 * LHdim) return;
    int o = (n & 3) * LHdim + (n >> 2);
    dst[n] = bih[o] + bhh[o];
}

// ---------------------------------------------------------------------------
__global__ __launch_bounds__(256) void norm_kernel(const float* __restrict__ f, float* __restrict__ invn)
{
    int row  = blockIdx.x * 4 + (threadIdx.x >> 6);
    int lane = threadIdx.x & 63;
    const float* fr = f + (size_t)row * Edim;
    float ss = 0.f;
    for (int t = lane; t < Edim; t += 64) { float v = fr[t]; ss = fmaf(v, v, ss); }
    #pragma unroll
    for (int o = 32; o > 0; o >>= 1) ss += __shfl_down(ss, o);
    if (lane == 0) invn[row] = 1.f / (sqrtf(ss) + 1e-8f);
}

__global__ __launch_bounds__(256) void simadj_kernel(
    const float* __restrict__ f, const float* __restrict__ invn,
    const float* __restrict__ entro, const float* __restrict__ alphap,
    const float* __restrict__ thrp, uint8_t* __restrict__ adj)
{
    int b = blockIdx.x;
    __shared__ float S[16][100];
    int tid = threadIdx.x;
    int i0 = (tid >> 4) * 6, j0 = (tid & 15) * 6;
    float acc[6][6];
    #pragma unroll
    for (int i = 0; i < 6; ++i)
        #pragma unroll
        for (int j = 0; j < 6; ++j) acc[i][j] = 0.f;
    const float* fb = f + (size_t)b * Ndim * Edim;

    for (int k0 = 0; k0 < Edim; k0 += 16) {
        __syncthreads();
        #pragma unroll
        for (int r = 0; r < 6; ++r) {
            int n = (tid >> 4) + r * 16;
            S[tid & 15][n] = fb[(size_t)n * Edim + k0 + (tid & 15)];
        }
        __syncthreads();
        #pragma unroll
        for (int kk = 0; kk < 16; ++kk) {
            float a[6], bb[6];
            #pragma unroll
            for (int u = 0; u < 6; ++u) a[u] = S[kk][i0 + u];
            #pragma unroll
            for (int u = 0; u < 6; ++u) bb[u] = S[kk][j0 + u];
            #pragma unroll
            for (int i = 0; i < 6; ++i)
                #pragma unroll
                for (int j = 0; j < 6; ++j)
                    acc[i][j] = fmaf(a[i], bb[j], acc[i][j]);
        }
    }

    float alpha = *alphap, thr = *thrp;
    float onem = 1.f - alpha;
    #pragma unroll
    for (int i = 0; i < 6; ++i) {
        int ii = i0 + i;
        float inv_i = invn[b * Ndim + ii];
        #pragma unroll
        for (int j = 0; j < 6; ++j) {
            int jj = j0 + j;
            float simv = acc[i][j] * inv_i * invn[b * Ndim + jj];
            float comb = alpha * entro[b * Ndim + jj] + onem * simv;
            adj[((size_t)b * Ndim + ii) * Ndim + jj] = (comb > thr) ? 1 : 0;
        }
    }
}

__global__ __launch_bounds__(256) void qk_kernel(
    const float* __restrict__ Hsrc, const float* __restrict__ wqk,
    float* __restrict__ q, float* __restrict__ k)
{
    int row  = blockIdx.x * 4 + (threadIdx.x >> 6);
    int lane = threadIdx.x & 63;
    const float* h = Hsrc + (size_t)row * GDdim;
    float sq = 0.f, sk = 0.f;
    for (int t = lane; t < HDdim; t += 64) {
        float hv = h[t];
        sq = fmaf(hv, wqk[t], sq);
        sk = fmaf(hv, wqk[HDdim + t], sk);
    }
    #pragma unroll
    for (int o = 32; o > 0; o >>= 1) { sq += __shfl_down(sq, o); sk += __shfl_down(sk, o); }
    if (lane == 0) { q[row] = sq; k[row] = sk; }
}

// ---------------------------------------------------------------------------
// Fused GAT attention for one batch b: softmax over j of (q_i+k_j+gb) masked
// by adj reduces to adj*e^{k_j}/sum (q_i, gb cancel). Then
// M[i,d] = sum_j P0[i,j]*V0[b,j,d] + P1[i,j]*V1[b,j,d], P0=attn*sm, P1=attn*(1-sm).
// One block per b; P and V tiles in LDS; 6x6 register tiles; 4 d-passes.
// ---------------------------------------------------------------------------
__global__ __launch_bounds__(256) void gat_fused(
    const float* __restrict__ kbuf, const uint8_t* __restrict__ adj,
    const int* __restrict__ smask,
    const float* __restrict__ V0, const float* __restrict__ V1,
    float* __restrict__ Mout)
{
    __shared__ float P0[96][98];
    __shared__ float P1[96][98];
    __shared__ float Vs0[96][96];
    __shared__ float Vs1[96][96];
    __shared__ float ek[96];
    __shared__ float rden[96];
    __shared__ float red[256];
    const int b = blockIdx.x;
    const int tid = threadIdx.x;

    float kj = (tid < Ndim) ? kbuf[tid * Bdim + b] : -1e30f;
    red[tid] = kj;
    __syncthreads();
    #pragma unroll
    for (int s = 128; s > 0; s >>= 1) {
        if (tid < s) red[tid] = fmaxf(red[tid], red[tid + s]);
        __syncthreads();
    }
    float kmax = red[0];
    if (tid < Ndim) ek[tid] = expf(kj - kmax);
    __syncthreads();
    if (tid < Ndim) {
        const uint8_t* ar = adj + ((size_t)b * Ndim + tid) * Ndim;
        float s = 0.f;
        for (int j = 0; j < Ndim; ++j) if (ar[j]) s += ek[j];
        rden[tid] = 1.f / s;   // diagonal always allowed -> s > 0
    }
    __syncthreads();
    for (int idx = tid; idx < Ndim * Ndim; idx += 256) {
        int i = idx / Ndim, j = idx - i * Ndim;
        float a = adj[((size_t)b * Ndim + i) * Ndim + j] ? ek[j] * rden[i] : 0.f;
        int s = smask[((size_t)b * Ndim + i) * Ndim + j];
        P0[i][j] = s ? a : 0.f;
        P1[i][j] = s ? 0.f : a;
    }
    __syncthreads();

    const int ti = tid >> 4, td = tid & 15;
    const int i0 = ti * 6, dbase = td * 6;
    for (int p = 0; p < 4; ++p) {
        const int d0 = p * 96;
        const int dw = (p == 3) ? (HDdim - 288) : 96;
        for (int idx = tid; idx < 96 * 24; idx += 256) {
            int j = idx / 24, q4 = (idx - j * 24) * 4;
            if (q4 < dw) {
                size_t g = ((size_t)(j * Bdim + b)) * HDdim + d0 + q4;
                *(float4*)&Vs0[j][q4] = *(const float4*)(V0 + g);
                *(float4*)&Vs1[j][q4] = *(const float4*)(V1 + g);
            }
        }
        __syncthreads();
        float acc[6][6];
        #pragma unroll
        for (int ii = 0; ii < 6; ++ii)
            #pragma unroll
            for (int dd = 0; dd < 6; ++dd) acc[ii][dd] = 0.f;
        for (int j = 0; j < Ndim; j += 2) {
            float2 pa[6], pb[6];
            #pragma unroll
            for (int ii = 0; ii < 6; ++ii) {
                pa[ii] = *(const float2*)&P0[i0 + ii][j];
                pb[ii] = *(const float2*)&P1[i0 + ii][j];
            }
            float2 v0a[3], v0b[3], v1a[3], v1b[3];
            #pragma unroll
            for (int dd = 0; dd < 3; ++dd) {
                v0a[dd] = *(const float2*)&Vs0[j][dbase + 2 * dd];
                v0b[dd] = *(const float2*)&Vs0[j + 1][dbase + 2 * dd];
                v1a[dd] = *(const float2*)&Vs1[j][dbase + 2 * dd];
                v1b[dd] = *(const float2*)&Vs1[j + 1][dbase + 2 * dd];
            }
            #pragma unroll
            for (int ii = 0; ii < 6; ++ii)
                #pragma unroll
                for (int dd = 0; dd < 3; ++dd) {
                    acc[ii][2*dd]   += pa[ii].x * v0a[dd].x + pb[ii].x * v1a[dd].x
                                     + pa[ii].y * v0b[dd].x + pb[ii].y * v1b[dd].x;
                    acc[ii][2*dd+1] += pa[ii].x * v0a[dd].y + pb[ii].x * v1a[dd].y
                                     + pa[ii].y * v0b[dd].y + pb[ii].y * v1b[dd].y;
                }
        }
        __syncthreads();
        #pragma unroll
        for (int ii = 0; ii < 6; ++ii) {
            #pragma unroll
            for (int dd = 0; dd < 6; ++dd) {
                int d = dbase + dd;
                if (d < dw)
                    Mout[((size_t)((i0 + ii) * Bdim + b)) * GDdim + d0 + d] = acc[ii][dd];
            }
        }
    }
}

__global__ __launch_bounds__(256) void zero_hc_kernel(float* __restrict__ h, float* __restrict__ c, int n)
{
    int i = blockIdx.x * 256 + threadIdx.x;
    if (i < n) { h[i] = 0.f; c[i] = 0.f; }
}

// ---------------------------------------------------------------------------
// Fused LSTM step v2: 64x64 tile, 256 threads, grid (4,38)=152 blocks.
// gates(b, n'=u*4+g) = h_in @ WhhP^T + zt; cell update; writes h/c/Hl.
// K=600 tail (8 cols) zero-guarded.
// ---------------------------------------------------------------------------
__global__ __launch_bounds__(256) void lstm_step2(
    const float* __restrict__ hin, const float* __restrict__ cin,
    const float* __restrict__ WhhP, const float* __restrict__ zt,
    float* __restrict__ hout, float* __restrict__ cout,
    float* __restrict__ Hl)
{
    __shared__ __align__(16) float As[16][68];
    __shared__ __align__(16) float Ws[16][68];
    const int bm = blockIdx.x * 64;
    const int bn = blockIdx.y * 64;
    const int tid = threadIdx.x;
    const int lm  = tid & 63;
    const int lk4 = (tid >> 6) << 2;
    const int tm = (tid >> 4) << 2;
    const int tn = (tid & 15) << 2;
    float acc[4][4] = {{0.f,0.f,0.f,0.f},{0.f,0.f,0.f,0.f},{0.f,0.f,0.f,0.f},{0.f,0.f,0.f,0.f}};
    const int am = bm + lm;            // < 256 always
    const int wn = bn + lm;
    const float4 fz = make_float4(0.f, 0.f, 0.f, 0.f);

    for (int k0 = 0; k0 < LHdim; k0 += 16) {
        const bool kv = (k0 + lk4 + 4 <= LHdim);   // whole float4 in range
        float4 av = kv ? *(const float4*)(hin + (size_t)am * LHdim + k0 + lk4) : fz;
        float4 wv = (kv && wn < 4 * LHdim)
                  ? *(const float4*)(WhhP + (size_t)wn * LHdim + k0 + lk4) : fz;
        __syncthreads();
        As[lk4+0][lm] = av.x; As[lk4+1][lm] = av.y; As[lk4+2][lm] = av.z; As[lk4+3][lm] = av.w;
        Ws[lk4+0][lm] = wv.x; Ws[lk4+1][lm] = wv.y; Ws[lk4+2][lm] = wv.z; Ws[lk4+3][lm] = wv.w;
        __syncthreads();
        #pragma unroll
        for (int kk = 0; kk < 16; ++kk) {
            float a0[4], w0[4];
            *(float4*)a0 = *(const float4*)&As[kk][tm];
            *(float4*)w0 = *(const float4*)&Ws[kk][tn];
            #pragma unroll
            for (int i = 0; i < 4; ++i)
                #pragma unroll
                for (int j = 0; j < 4; ++j)
                    acc[i][j] = fmaf(a0[i], w0[j], acc[i][j]);
        }
    }

    const int n0 = bn + tn;
    if (n0 < 4 * LHdim) {
        const int u = n0 >> 2;
        #pragma unroll
        for (int i = 0; i < 4; ++i) {
            int bb = bm + tm + i;
            const float* z = zt + (size_t)bb * (4 * LHdim) + n0;
            float gi = acc[i][0] + z[0];
            float gf = acc[i][1] + z[1];
            float gg = acc[i][2] + z[2];
            float go = acc[i][3] + z[3];
            float si = 1.f / (1.f + expf(-gi));
            float sf = 1.f / (1.f + expf(-gf));
            float so = 1.f / (1.f + expf(-go));
            float cn = sf * cin[bb * LHdim + u] + si * tanhf(gg);
            float hn = so * tanhf(cn);
            cout[bb * LHdim + u] = cn;
            hout[bb * LHdim + u] = hn;
            Hl[bb * LHdim + u]   = hn;
        }
    }
}

__global__ __launch_bounds__(256) void out_kernel(
    const float* __restrict__ x, const float* __restrict__ ow,
    const float* __restrict__ ob, float* __restrict__ out)
{
    int r    = blockIdx.x * 4 + (threadIdx.x >> 6);
    int lane = threadIdx.x & 63;
    const float* xr = x + (size_t)r * HDdim;
    float acc[NCdim];
    #pragma unroll
    for (int n = 0; n < NCdim; ++n) acc[n] = 0.f;
    for (int t = lane; t < HDdim; t += 64) {
        float xv = xr[t];
        #pragma unroll
        for (int n = 0; n < NCdim; ++n) acc[n] = fmaf(xv, ow[n * HDdim + t], acc[n]);
    }
    #pragma unroll
    for (int o = 32; o > 0; o >>= 1)
        #pragma unroll
        for (int n = 0; n < NCdim; ++n) acc[n] += __shfl_down(acc[n], o);
    if (lane == 0) {
        int b = r & 255, nn = r >> 8;
        #pragma unroll
        for (int n = 0; n < NCdim; ++n) out[((size_t)b * Ndim + nn) * NCdim + n] = acc[n] + ob[n];
    }
}

// ---------------------------------------------------------------------------
extern "C" void kernel_launch(void* const* d_in, const int* in_sizes, int n_in,
                              void* d_out, int out_size, void* d_ws, size_t ws_size,
                              hipStream_t stream)
{
    const float*  features  = (const float*)d_in[0];
    const int*    s_mask    = (const int*)  d_in[1];
    const float*  entro     = (const float*)d_in[2];
    const float*  alpha     = (const float*)d_in[3];
    const float*  threshold = (const float*)d_in[4];
    const float*  fc1_w     = (const float*)d_in[5];
    const float*  fc1_b     = (const float*)d_in[6];
    const float*  gat_w     = (const float*)d_in[7];
    const float*  gat_b     = (const float*)d_in[8];
    const float*  wr0       = (const float*)d_in[9];
    const float*  wr1       = (const float*)d_in[10];
    const float*  enhance_w = (const float*)d_in[11];
    const float*  enhance_b = (const float*)d_in[12];
    const float*  prelu_a   = (const float*)d_in[13];
    const float*  lstm_w_ih = (const float*)d_in[14];
    const float*  lstm_w_hh = (const float*)d_in[15];
    const float*  lstm_b_ih = (const float*)d_in[16];
    const float*  lstm_b_hh = (const float*)d_in[17];
    const float*  mlp_w0    = (const float*)d_in[18];
    const float*  mlp_b0    = (const float*)d_in[19];
    const float*  mlp_a0    = (const float*)d_in[20];
    const float*  mlp_w1    = (const float*)d_in[21];
    const float*  mlp_b1    = (const float*)d_in[22];
    const float*  mlp_a1    = (const float*)d_in[23];
    const float*  out_w     = (const float*)d_in[24];
    const float*  out_b     = (const float*)d_in[25];
    float* out = (float*)d_out;
    char* ws = (char*)d_ws;

    // ---- fixed workspace layout (bytes, 256-aligned) ----
    uint8_t* adj   = (uint8_t*)(ws + 0);               //  2,359,296
    float*   invn  = (float*)(ws + 2359296);
    float*   qbuf  = (float*)(ws + 2457600);
    float*   kbuf  = (float*)(ws + 2555904);
    float*   biasP = (float*)(ws + 2654208);
    float*   h0    = (float*)(ws + 2663936);
    float*   c0    = (float*)(ws + 3278336);
    float*   h1    = (float*)(ws + 3892736);
    float*   c1    = (float*)(ws + 4507136);
    float*   WhhP  = (float*)(ws + 5121536);           //  5,760,000
    u16*     WihPH = (u16*)(ws + 10881536);            //  9,494,528 (2432 x 1952, rows 2400+ zero)
    u16*     WihPL = (u16*)(ws + 20376064);
    u16*     EwH   = (u16*)(ws + 29870592);            //  2,097,152 (1024 x 1024)
    u16*     EwL   = (u16*)(ws + 31967744);
    float*   Hcat  = (float*)(ws + 34064896);          // 88,473,600 (ROWS,900) n-major
    float*   V0    = (float*)(ws + 122538496);         // 29,491,200 (GAT)    } alias
    float*   V1    = (float*)(ws + 152029696);         // 29,491,200 (GAT)    } Hlstm
    float*   Hlstm = V0;                               // 58,982,400 (ROWS,600)
    float*   x1    = Hcat;                             // MLP scratch (Hcat dead)
    float*   x2    = (float*)(ws + 63556096);          // Hcat + 29,491,200 B

    // ---- tier selection for chunked seq/zin region ----
    const size_t fixedNeed = 181520896ull;
    const size_t perT = 5505024ull;                    // bytes per time-step
    int T;
    if      (ws_size >= fixedNeed + 96ull * perT) T = 96;
    else if (ws_size >= fixedNeed + 32ull * perT) T = 32;
    else if (ws_size >= fixedNeed + 16ull * perT) T = 16;
    else if (ws_size >= fixedNeed +  8ull * perT) T = 8;
    else if (ws_size >= fixedNeed +  4ull * perT) T = 4;
    else return;                                       // visible failure, no OOB
    char* cr = ws + fixedNeed;
    u16*   FHc  = (u16*)cr;                                         // (Mc,1024)
    u16*   FLc  = (u16*)(cr + (size_t)T *  524288);
    u16*   seqH = (u16*)(cr + (size_t)T * 1048576);                 // (Mc,1952)
    u16*   seqL = (u16*)(cr + (size_t)T * 1048576 + (size_t)T * 999424);
    float* zin  = (float*)(cr + (size_t)T * 1048576 + (size_t)T * 1998848);  // (Mc,2400)

    // 1) norms + adjacency
    norm_kernel<<<ROWS / 4, 256, 0, stream>>>(features, invn);
    simadj_kernel<<<Bdim, 256, 0, stream>>>(features, invn, entro, alpha, threshold, adj);

    // 2) H0 = prelu(features @ fc1_w^T + fc1_b) -> Hcat[:, 0:300] (n-major)
    gemm_tn<1,0><<<dim3(ROWS/64, 5), 256, 0, stream>>>(
        features, Edim, 255, Ndim, 8, 1, 0,
        fc1_w, Edim, Hcat, GDdim, ROWS, HDdim, Edim, fc1_b, nullptr, prelu_a);

    // 3) GAT layers (fused softmax+aggregation; q/gb cancel in softmax)
    for (int l = 0; l < Ldim; ++l) {
        const float* Hsrc = Hcat + l * HDdim;
        qk_kernel<<<ROWS / 4, 256, 0, stream>>>(Hsrc, gat_w + l * 2 * HDdim, qbuf, kbuf);
        gemm_tn<0,0><<<dim3(ROWS/64, 5), 256, 0, stream>>>(
            Hsrc, GDdim, IDP, wr0 + (size_t)l * HDdim * HDdim, HDdim,
            V0, HDdim, ROWS, HDdim, HDdim, nullptr, nullptr, nullptr);
        gemm_tn<0,0><<<dim3(ROWS/64, 5), 256, 0, stream>>>(
            Hsrc, GDdim, IDP, wr1 + (size_t)l * HDdim * HDdim, HDdim,
            V1, HDdim, ROWS, HDdim, HDdim, nullptr, nullptr, nullptr);
        gat_fused<<<Bdim, 256, 0, stream>>>(
            kbuf, adj, s_mask, V0, V1, Hcat + (l + 1) * HDdim);
    }

    // 4) weight conversions (bf16 hi/lo, gate-interleaved perms), state init
    split_rows<<<dim3(8, 2432), 256, 0, stream>>>(
        lstm_w_ih, Edim + GDdim, 3, LHdim, 2, 1, 0, WihPH, WihPL, 1952, 1952, 1924, 2400);
    split_rows<<<dim3(4, Edim), 256, 0, stream>>>(
        enhance_w, Edim, IDP, EwH, EwL, Edim, Edim, Edim, Edim);
    whh_perm<<<dim3(3, 4 * LHdim), 256, 0, stream>>>(lstm_w_hh, WhhP);
    bias_perm<<<10, 256, 0, stream>>>(lstm_b_ih, lstm_b_hh, biasP);
    zero_hc_kernel<<<600, 256, 0, stream>>>(h0, c0, Bdim * LHdim);

    // 5) chunked: feat split -> enhance MFMA -> Hcat split -> zin MFMA -> LSTM
    float* hb[2] = {h0, h1};
    float* cb[2] = {c0, c1};
    int cur = 0;
    for (int t0 = 0; t0 < Ndim; t0 += T) {
        int Mc = T * Bdim;
        split_rows<<<dim3(4, Mc), 256, 0, stream>>>(
            features, Edim, 255, Ndim, 8, 1, t0, FHc, FLc, Edim, Edim, Edim, Mc);
        gemm_mfma3<1,1><<<dim3(Mc/128, 8), 256, 0, stream>>>(
            FHc, FLc, Edim, EwH, EwL, Edim,
            nullptr, seqH, seqL, 1952, Mc, Edim, Edim, enhance_b, prelu_a);
        split_rows<<<dim3(4, Mc), 256, 0, stream>>>(
            Hcat, GDdim, 0x7FFFFFFF, 1, 30, 0, t0 * Bdim,
            seqH + 1024, seqL + 1024, 1952, 928, GDdim, Mc);
        gemm_mfma3<0,0><<<dim3(Mc/128, 19), 256, 0, stream>>>(
            seqH, seqL, 1952, WihPH, WihPL, 1952,
            zin, nullptr, nullptr, 4 * LHdim, Mc, 4 * LHdim, 1952, biasP, nullptr);
        for (int tl = 0; tl < T; ++tl) {
            lstm_step2<<<dim3(4, 38), 256, 0, stream>>>(
                hb[cur], cb[cur], WhhP, zin + (size_t)tl * Bdim * 4 * LHdim,
                hb[cur ^ 1], cb[cur ^ 1],
                Hlstm + (size_t)(t0 + tl) * Bdim * LHdim);
            cur ^= 1;
        }
    }

    // 6) MLP head + output
    gemm_tn<1,0><<<dim3(ROWS/64, 5), 256, 0, stream>>>(
        Hlstm, LHdim, IDP, mlp_w0, LHdim, x1, HDdim, ROWS, HDdim, LHdim, mlp_b0, nullptr, mlp_a0);
    gemm_tn<1,0><<<dim3(ROWS/64, 5), 256, 0, stream>>>(
        x1, HDdim, IDP, mlp_w1, HDdim, x2, HDdim, ROWS, HDdim, HDdim, mlp_b1, nullptr, mlp_a1);
    out_kernel<<<ROWS / 4, 256, 0, stream>>>(x2, out_w, out_b, out);
}

// Round 7
// 7925.378 us; speedup vs baseline: 1.3377x; 1.3377x over previous
//
#include <hip/hip_runtime.h>
#include <cstdint>
#include <cstddef>

#define Bdim 256
#define Ndim 96
#define Edim 1024
#define HDdim 300
#define Ldim 2
#define LHdim 600
#define NCdim 7
#define GDdim 900              // HD*(L+1)
#define ROWS (Bdim*Ndim)       // 24576

typedef unsigned short u16;
typedef float f32x4 __attribute__((ext_vector_type(4)));
typedef short bf16x8 __attribute__((ext_vector_type(8)));

// Identity row-perm constants
#define IDP 0x7FFFFFFF, 1, 30, 0, 0

__device__ inline u16 f2bf(float x) {
    unsigned int u = __builtin_bit_cast(unsigned int, x);
    unsigned int r = (u + 0x7fffu + ((u >> 16) & 1u)) >> 16;   // RNE
    return (u16)r;
}
__device__ inline float bf2f(u16 h) {
    unsigned int u = ((unsigned int)h) << 16;
    return __builtin_bit_cast(float, u);
}

// ---------------------------------------------------------------------------
// fp32 GEMM (fc1 / GAT V / MLP): C[m,n]=act(sum_k A[rowA(m),k]W[n,k]+b)
// ---------------------------------------------------------------------------
template<int ACT, int ACC>
__global__ __launch_bounds__(256) void gemm_tn(
    const float* __restrict__ A, int lda,
    int pmask, int pmul1, int pshift, int pmul2, int padd,
    const float* __restrict__ W, int ldw,
    float* __restrict__ C, int ldc,
    int M, int Nd, int K,
    const float* __restrict__ bias1,
    const float* __restrict__ bias2,
    const float* __restrict__ aptr)
{
    __shared__ __align__(16) float As[16][68];
    __shared__ __align__(16) float Ws[16][68];
    const int bm = blockIdx.x * 64;
    const int bn = blockIdx.y * 64;
    const int tid = threadIdx.x;
    const int lm  = tid & 63;
    const int lk4 = (tid >> 6) << 2;
    const int tm = (tid >> 4) << 2;
    const int tn = (tid & 15) << 2;
    float acc[4][4] = {{0.f,0.f,0.f,0.f},{0.f,0.f,0.f,0.f},{0.f,0.f,0.f,0.f},{0.f,0.f,0.f,0.f}};
    const int am = bm + lm;
    const int wn = bn + lm;
    const int rowA = (am & pmask) * pmul1 + (am >> pshift) * pmul2 + padd;

    for (int k0 = 0; k0 < K; k0 += 16) {
        float4 av, wv;
        const bool fullk = (k0 + 16 <= K);
        if (fullk) {
            av = (am < M)  ? *(const float4*)(A + (size_t)rowA * lda + k0 + lk4) : make_float4(0.f,0.f,0.f,0.f);
            wv = (wn < Nd) ? *(const float4*)(W + (size_t)wn   * ldw + k0 + lk4) : make_float4(0.f,0.f,0.f,0.f);
        } else {
            float ta[4], tw[4];
            #pragma unroll
            for (int u = 0; u < 4; ++u) {
                int k = k0 + lk4 + u;
                ta[u] = (am < M  && k < K) ? A[(size_t)rowA * lda + k] : 0.f;
                tw[u] = (wn < Nd && k < K) ? W[(size_t)wn   * ldw + k] : 0.f;
            }
            av = make_float4(ta[0],ta[1],ta[2],ta[3]);
            wv = make_float4(tw[0],tw[1],tw[2],tw[3]);
        }
        __syncthreads();
        As[lk4+0][lm] = av.x; As[lk4+1][lm] = av.y; As[lk4+2][lm] = av.z; As[lk4+3][lm] = av.w;
        Ws[lk4+0][lm] = wv.x; Ws[lk4+1][lm] = wv.y; Ws[lk4+2][lm] = wv.z; Ws[lk4+3][lm] = wv.w;
        __syncthreads();
        #pragma unroll
        for (int kk = 0; kk < 16; ++kk) {
            float a0[4], w0[4];
            *(float4*)a0 = *(const float4*)&As[kk][tm];
            *(float4*)w0 = *(const float4*)&Ws[kk][tn];
            #pragma unroll
            for (int i = 0; i < 4; ++i)
                #pragma unroll
                for (int j = 0; j < 4; ++j)
                    acc[i][j] = fmaf(a0[i], w0[j], acc[i][j]);
        }
    }

    const float aval = (ACT == 1) ? *aptr : 0.f;
    #pragma unroll
    for (int i = 0; i < 4; ++i) {
        int m = bm + tm + i;
        if (m >= M) continue;
        #pragma unroll
        for (int j = 0; j < 4; ++j) {
            int n = bn + tn + j;
            if (n >= Nd) continue;
            float v = acc[i][j];
            if (bias1) v += bias1[n];
            if (bias2) v += bias2[n];
            if (ACC)   v += C[(size_t)m * ldc + n];
            if (ACT == 1) v = (v >= 0.f) ? v : aval * v;
            C[(size_t)m * ldc + n] = v;
        }
    }
}

// ---------------------------------------------------------------------------
// bf16x3 split MFMA GEMM (round-4 proven staging: reg->LDS, 415us zin).
// C = act(sum_k (Ah+Al)[m,k]*(Wh+Wl)[n,k] + bias). K mult of 32; lda/ldw mult 8.
// OUT: 0 -> fp32 C; 1 -> split bf16 (Ch,Cl). ACT: 1 -> prelu(aptr).
// Tile 128x128, BK=32, 4 waves (2x2), wave tile 64x64 = 4x4 frags of 16x16x32.
// ---------------------------------------------------------------------------
template<int OUT, int ACT>
__global__ __launch_bounds__(256) void gemm_mfma3(
    const u16* __restrict__ Ah, const u16* __restrict__ Al, int lda,
    const u16* __restrict__ Wh, const u16* __restrict__ Wl, int ldw,
    float* __restrict__ C, u16* __restrict__ Ch, u16* __restrict__ Cl, int ldc,
    int M, int Nd, int K,
    const float* __restrict__ bias, const float* __restrict__ aptr)
{
    __shared__ u16 AtH[4][1024];
    __shared__ u16 AtL[4][1024];
    __shared__ u16 WtH[4][1024];
    __shared__ u16 WtL[4][1024];
    const int tid  = threadIdx.x;
    const int bm   = blockIdx.x * 128;
    const int bn   = blockIdx.y * 128;
    const int wv   = tid >> 6;
    const int lane = tid & 63;
    const int wr   = (wv >> 1) * 64;
    const int wc   = (wv & 1) * 64;
    const int l15  = lane & 15;
    const int kseg = lane >> 4;

    f32x4 acc[4][4];
    #pragma unroll
    for (int i = 0; i < 4; ++i)
        #pragma unroll
        for (int j = 0; j < 4; ++j) acc[i][j] = (f32x4){0.f,0.f,0.f,0.f};

    const int srow = tid & 127;
    const bool isA = (tid < 128);
    const int gr   = isA ? (bm + srow) : (bn + srow);
    const int glim = isA ? M : Nd;
    const u16* pHbase = (isA ? Ah : Wh) + (size_t)gr * (isA ? lda : ldw);
    const u16* pLbase = (isA ? Al : Wl) + (size_t)gr * (isA ? lda : ldw);
    u16* dH = isA ? &AtH[0][0] : &WtH[0][0];
    u16* dL = isA ? &AtL[0][0] : &WtL[0][0];

    for (int k0 = 0; k0 < K; k0 += 32) {
        __syncthreads();
        {
            const bool ok = (gr < glim);
            #pragma unroll
            for (int s = 0; s < 4; ++s) {
                bf16x8 vH = {0,0,0,0,0,0,0,0};
                bf16x8 vL = {0,0,0,0,0,0,0,0};
                if (ok) {
                    vH = *(const bf16x8*)(pHbase + k0 + s * 8);
                    vL = *(const bf16x8*)(pLbase + k0 + s * 8);
                }
                *(bf16x8*)(dH + s * 1024 + srow * 8) = vH;
                *(bf16x8*)(dL + s * 1024 + srow * 8) = vL;
            }
        }
        __syncthreads();
        bf16x8 aH[4], aL[4], bH[4], bL[4];
        #pragma unroll
        for (int f = 0; f < 4; ++f) {
            int ar = wr + f * 16 + l15;
            int br = wc + f * 16 + l15;
            aH[f] = *(const bf16x8*)&AtH[kseg][ar * 8];
            aL[f] = *(const bf16x8*)&AtL[kseg][ar * 8];
            bH[f] = *(const bf16x8*)&WtH[kseg][br * 8];
            bL[f] = *(const bf16x8*)&WtL[kseg][br * 8];
        }
        #pragma unroll
        for (int i = 0; i < 4; ++i)
            #pragma unroll
            for (int j = 0; j < 4; ++j)
                acc[i][j] = __builtin_amdgcn_mfma_f32_16x16x32_bf16(aH[i], bH[j], acc[i][j], 0, 0, 0);
        #pragma unroll
        for (int i = 0; i < 4; ++i)
            #pragma unroll
            for (int j = 0; j < 4; ++j)
                acc[i][j] = __builtin_amdgcn_mfma_f32_16x16x32_bf16(aH[i], bL[j], acc[i][j], 0, 0, 0);
        #pragma unroll
        for (int i = 0; i < 4; ++i)
            #pragma unroll
            for (int j = 0; j < 4; ++j)
                acc[i][j] = __builtin_amdgcn_mfma_f32_16x16x32_bf16(aL[i], bH[j], acc[i][j], 0, 0, 0);
    }

    const float av = (ACT == 1) ? *aptr : 0.f;
    const int r4 = (lane >> 4) * 4;
    #pragma unroll
    for (int j = 0; j < 4; ++j) {
        int col = bn + wc + j * 16 + l15;
        if (col >= Nd) continue;
        float bv = bias ? bias[col] : 0.f;
        #pragma unroll
        for (int i = 0; i < 4; ++i) {
            #pragma unroll
            for (int rr = 0; rr < 4; ++rr) {
                int row = bm + wr + i * 16 + r4 + rr;
                if (row >= M) continue;
                float v = acc[i][j][rr] + bv;
                if (ACT == 1) v = (v >= 0.f) ? v : av * v;
                if (OUT == 0) {
                    C[(size_t)row * ldc + col] = v;
                } else {
                    u16 h = f2bf(v);
                    Ch[(size_t)row * ldc + col] = h;
                    Cl[(size_t)row * ldc + col] = f2bf(v - bf2f(h));
                }
            }
        }
    }
}

// ---------------------------------------------------------------------------
// split fp32 -> bf16 hi/lo with row perm, col/row zero-pad.
// ---------------------------------------------------------------------------
__global__ __launch_bounds__(256) void split_rows(
    const float* __restrict__ src, int srcld,
    int pmask, int pmul1, int pshift, int pmul2, int padd,
    u16* __restrict__ dstH, u16* __restrict__ dstL, int dstld,
    int wcols, int validK, int validRows)
{
    int r = blockIdx.y;
    int c = blockIdx.x * 256 + threadIdx.x;
    if (c >= wcols) return;
    int sr = (r & pmask) * pmul1 + (r >> pshift) * pmul2 + padd;
    float v = 0.f;
    if (c < validK && r < validRows) v = src[(size_t)sr * srcld + c];
    u16 h = f2bf(v);
    dstH[(size_t)r * dstld + c] = h;
    dstL[(size_t)r * dstld + c] = f2bf(v - bf2f(h));
}

// Whh rows permuted to gate-interleaved order: row' = u*4+g
__global__ __launch_bounds__(256) void whh_perm(const float* __restrict__ src, float* __restrict__ dst)
{
    int r = blockIdx.y;
    int c = blockIdx.x * 256 + threadIdx.x;
    if (c >= LHdim) return;
    int sr = (r & 3) * LHdim + (r >> 2);
    dst[(size_t)r * LHdim + c] = src[(size_t)sr * LHdim + c];
}

// biasP[n'] = b_ih[orig]+b_hh[orig], orig = (n'&3)*600+(n'>>2)
__global__ __launch_bounds__(256) void bias_perm(
    const float* __restrict__ bih, const float* __restrict__ bhh, float* __restrict__ dst)
{
    int n = blockIdx.x * 256 + threadIdx.x;
    if (n >= 4 * LHdim) return;
    int o = (n & 3) * LHdim + (n >> 2);
    dst[n] = bih[o] + bhh[o];
}

// Wr2[l][r][c]: r<300 -> wr0[l][r][c], else wr1[l][r-300][c]
__global__ __launch_bounds__(256) void wr_cat(
    const float* __restrict__ wr0, const float* __restrict__ wr1, float* __restrict__ dst)
{
    int c = blockIdx.x * 256 + threadIdx.x;
    if (c >= HDdim) return;
    int lr = blockIdx.y;
    int l = lr / (2 * HDdim), r = lr % (2 * HDdim);
    const float* src = (r < HDdim)
        ? wr0 + ((size_t)l * HDdim + r) * HDdim
        : wr1 + ((size_t)l * HDdim + (r - HDdim)) * HDdim;
    dst[(size_t)lr * HDdim + c] = src[c];
}

// ---------------------------------------------------------------------------
__global__ __launch_bounds__(256) void norm_kernel(const float* __restrict__ f, float* __restrict__ invn)
{
    int row  = blockIdx.x * 4 + (threadIdx.x >> 6);
    int lane = threadIdx.x & 63;
    const float* fr = f + (size_t)row * Edim;
    float ss = 0.f;
    for (int t = lane; t < Edim; t += 64) { float v = fr[t]; ss = fmaf(v, v, ss); }
    #pragma unroll
    for (int o = 32; o > 0; o >>= 1) ss += __shfl_down(ss, o);
    if (lane == 0) invn[row] = 1.f / (sqrtf(ss) + 1e-8f);
}

__global__ __launch_bounds__(256) void simadj_kernel(
    const float* __restrict__ f, const float* __restrict__ invn,
    const float* __restrict__ entro, const float* __restrict__ alphap,
    const float* __restrict__ thrp, uint8_t* __restrict__ adj)
{
    int b = blockIdx.x;
    __shared__ float S[16][100];
    int tid = threadIdx.x;
    int i0 = (tid >> 4) * 6, j0 = (tid & 15) * 6;
    float acc[6][6];
    #pragma unroll
    for (int i = 0; i < 6; ++i)
        #pragma unroll
        for (int j = 0; j < 6; ++j) acc[i][j] = 0.f;
    const float* fb = f + (size_t)b * Ndim * Edim;

    for (int k0 = 0; k0 < Edim; k0 += 16) {
        __syncthreads();
        #pragma unroll
        for (int r = 0; r < 6; ++r) {
            int n = (tid >> 4) + r * 16;
            S[tid & 15][n] = fb[(size_t)n * Edim + k0 + (tid & 15)];
        }
        __syncthreads();
        #pragma unroll
        for (int kk = 0; kk < 16; ++kk) {
            float a[6], bb[6];
            #pragma unroll
            for (int u = 0; u < 6; ++u) a[u] = S[kk][i0 + u];
            #pragma unroll
            for (int u = 0; u < 6; ++u) bb[u] = S[kk][j0 + u];
            #pragma unroll
            for (int i = 0; i < 6; ++i)
                #pragma unroll
                for (int j = 0; j < 6; ++j)
                    acc[i][j] = fmaf(a[i], bb[j], acc[i][j]);
        }
    }

    float alpha = *alphap, thr = *thrp;
    float onem = 1.f - alpha;
    #pragma unroll
    for (int i = 0; i < 6; ++i) {
        int ii = i0 + i;
        float inv_i = invn[b * Ndim + ii];
        #pragma unroll
        for (int j = 0; j < 6; ++j) {
            int jj = j0 + j;
            float simv = acc[i][j] * inv_i * invn[b * Ndim + jj];
            float comb = alpha * entro[b * Ndim + jj] + onem * simv;
            adj[((size_t)b * Ndim + ii) * Ndim + jj] = (comb > thr) ? 1 : 0;
        }
    }
}

__global__ __launch_bounds__(256) void qk_kernel(
    const float* __restrict__ Hsrc, const float* __restrict__ wqk,
    float* __restrict__ q, float* __restrict__ k)
{
    int row  = blockIdx.x * 4 + (threadIdx.x >> 6);
    int lane = threadIdx.x & 63;
    const float* h = Hsrc + (size_t)row * GDdim;
    float sq = 0.f, sk = 0.f;
    for (int t = lane; t < HDdim; t += 64) {
        float hv = h[t];
        sq = fmaf(hv, wqk[t], sq);
        sk = fmaf(hv, wqk[HDdim + t], sk);
    }
    #pragma unroll
    for (int o = 32; o > 0; o >>= 1) { sq += __shfl_down(sq, o); sk += __shfl_down(sk, o); }
    if (lane == 0) { q[row] = sq; k[row] = sk; }
}

// ---------------------------------------------------------------------------
// Fused GAT attention for one batch b (q, gat_b cancel in softmax).
// V combined: cols 0..299 = V0, 300..599 = V1, row stride 600 (n-major rows).
// ---------------------------------------------------------------------------
__global__ __launch_bounds__(256) void gat_fused(
    const float* __restrict__ kbuf, const uint8_t* __restrict__ adj,
    const int* __restrict__ smask,
    const float* __restrict__ V,
    float* __restrict__ Mout)
{
    __shared__ float P0[96][98];
    __shared__ float P1[96][98];
    __shared__ float Vs0[96][96];
    __shared__ float Vs1[96][96];
    __shared__ float ek[96];
    __shared__ float rden[96];
    __shared__ float red[256];
    const int b = blockIdx.x;
    const int tid = threadIdx.x;

    float kj = (tid < Ndim) ? kbuf[tid * Bdim + b] : -1e30f;
    red[tid] = kj;
    __syncthreads();
    #pragma unroll
    for (int s = 128; s > 0; s >>= 1) {
        if (tid < s) red[tid] = fmaxf(red[tid], red[tid + s]);
        __syncthreads();
    }
    float kmax = red[0];
    if (tid < Ndim) ek[tid] = expf(kj - kmax);
    __syncthreads();
    if (tid < Ndim) {
        const uint8_t* ar = adj + ((size_t)b * Ndim + tid) * Ndim;
        float s = 0.f;
        for (int j = 0; j < Ndim; ++j) if (ar[j]) s += ek[j];
        rden[tid] = 1.f / s;   // diagonal always allowed -> s > 0
    }
    __syncthreads();
    for (int idx = tid; idx < Ndim * Ndim; idx += 256) {
        int i = idx / Ndim, j = idx - i * Ndim;
        float a = adj[((size_t)b * Ndim + i) * Ndim + j] ? ek[j] * rden[i] : 0.f;
        int s = smask[((size_t)b * Ndim + i) * Ndim + j];
        P0[i][j] = s ? a : 0.f;
        P1[i][j] = s ? 0.f : a;
    }
    __syncthreads();

    const int ti = tid >> 4, td = tid & 15;
    const int i0 = ti * 6, dbase = td * 6;
    for (int p = 0; p < 4; ++p) {
        const int d0 = p * 96;
        const int dw = (p == 3) ? (HDdim - 288) : 96;
        for (int idx = tid; idx < 96 * 24; idx += 256) {
            int j = idx / 24, q4 = (idx - j * 24) * 4;
            if (q4 < dw) {
                size_t g = ((size_t)(j * Bdim + b)) * (2 * HDdim) + d0 + q4;
                *(float4*)&Vs0[j][q4] = *(const float4*)(V + g);
                *(float4*)&Vs1[j][q4] = *(const float4*)(V + g + HDdim);
            }
        }
        __syncthreads();
        float acc[6][6];
        #pragma unroll
        for (int ii = 0; ii < 6; ++ii)
            #pragma unroll
            for (int dd = 0; dd < 6; ++dd) acc[ii][dd] = 0.f;
        for (int j = 0; j < Ndim; j += 2) {
            float2 pa[6], pb[6];
            #pragma unroll
            for (int ii = 0; ii < 6; ++ii) {
                pa[ii] = *(const float2*)&P0[i0 + ii][j];
                pb[ii] = *(const float2*)&P1[i0 + ii][j];
            }
            float2 v0a[3], v0b[3], v1a[3], v1b[3];
            #pragma unroll
            for (int dd = 0; dd < 3; ++dd) {
                v0a[dd] = *(const float2*)&Vs0[j][dbase + 2 * dd];
                v0b[dd] = *(const float2*)&Vs0[j + 1][dbase + 2 * dd];
                v1a[dd] = *(const float2*)&Vs1[j][dbase + 2 * dd];
                v1b[dd] = *(const float2*)&Vs1[j + 1][dbase + 2 * dd];
            }
            #pragma unroll
            for (int ii = 0; ii < 6; ++ii)
                #pragma unroll
                for (int dd = 0; dd < 3; ++dd) {
                    acc[ii][2*dd]   += pa[ii].x * v0a[dd].x + pb[ii].x * v1a[dd].x
                                     + pa[ii].y * v0b[dd].x + pb[ii].y * v1b[dd].x;
                    acc[ii][2*dd+1] += pa[ii].x * v0a[dd].y + pb[ii].x * v1a[dd].y
                                     + pa[ii].y * v0b[dd].y + pb[ii].y * v1b[dd].y;
                }
        }
        __syncthreads();
        #pragma unroll
        for (int ii = 0; ii < 6; ++ii) {
            #pragma unroll
            for (int dd = 0; dd < 6; ++dd) {
                int d = dbase + dd;
                if (d < dw)
                    Mout[((size_t)((i0 + ii) * Bdim + b)) * GDdim + d0 + d] = acc[ii][dd];
            }
        }
    }
}

__global__ __launch_bounds__(256) void zero_hc_kernel(float* __restrict__ h, float* __restrict__ c, int n)
{
    int i = blockIdx.x * 256 + threadIdx.x;
    if (i < n) { h[i] = 0.f; c[i] = 0.f; }
}

// ---------------------------------------------------------------------------
// Fused LSTM step v3: 32x64 tile, 256 threads, grid (8,38)=304 blocks
// (all CUs busy), explicit prefetch pipeline. Epilogue/load guards for the
// 2432-vs-2400 gate-column overhang (grid.y*64 > 4*LH).
// ---------------------------------------------------------------------------
__global__ __launch_bounds__(256) void lstm_step3(
    const float* __restrict__ hin, const float* __restrict__ cin,
    const float* __restrict__ WhhP, const float* __restrict__ zt,
    float* __restrict__ hout, float* __restrict__ cout,
    float* __restrict__ Hl)
{
    __shared__ __align__(16) float Ht[16][36];
    __shared__ __align__(16) float Ws[16][68];
    const int bm = blockIdx.x * 32;
    const int bn = blockIdx.y * 64;
    const int tid = threadIdx.x;
    const int tm = (tid >> 4) << 1;       // 0..30 (2 rows)
    const int tn = (tid & 15) << 2;       // 0..60 (4 cols)
    float acc[2][4] = {{0.f,0.f,0.f,0.f},{0.f,0.f,0.f,0.f}};
    const int hb = tid & 31, hk = ((tid >> 5) & 3) << 2;   // 128 stagers for H
    const bool hstage = (tid < 128);
    const int wn = tid & 63, wk = (tid >> 6) << 2;          // 256 stagers for W
    const int gn = bn + wn;
    const bool gok = (gn < 4 * LHdim);                      // row exists in WhhP
    const float4 fz = make_float4(0.f, 0.f, 0.f, 0.f);

    const float* hrow = hin + (size_t)(bm + hb) * LHdim + hk;
    const float* wrow = WhhP + (size_t)(gok ? gn : 0) * LHdim + wk;

    // preload k0 = 0
    float4 av = hstage ? *(const float4*)hrow : fz;
    float4 wv = gok ? *(const float4*)wrow : fz;

    for (int k0 = 0; k0 < LHdim; k0 += 16) {
        __syncthreads();       // protect LDS reads of previous iteration
        if (hstage) {
            Ht[hk+0][hb] = av.x; Ht[hk+1][hb] = av.y; Ht[hk+2][hb] = av.z; Ht[hk+3][hb] = av.w;
        }
        Ws[wk+0][wn] = wv.x; Ws[wk+1][wn] = wv.y; Ws[wk+2][wn] = wv.z; Ws[wk+3][wn] = wv.w;
        // prefetch k0+16 (600-tail: whole-float4 in range or zero)
        const int k1 = k0 + 16;
        if (k1 < LHdim) {
            av = (hstage && (k1 + hk + 4 <= LHdim)) ? *(const float4*)(hrow + k1) : fz;
            wv = (gok && (k1 + wk + 4 <= LHdim)) ? *(const float4*)(wrow + k1) : fz;
        }
        __syncthreads();
        #pragma unroll
        for (int kk = 0; kk < 16; ++kk) {
            float2 a0 = *(const float2*)&Ht[kk][tm];
            float w0[4];
            *(float4*)w0 = *(const float4*)&Ws[kk][tn];
            #pragma unroll
            for (int j = 0; j < 4; ++j) {
                acc[0][j] = fmaf(a0.x, w0[j], acc[0][j]);
                acc[1][j] = fmaf(a0.y, w0[j], acc[1][j]);
            }
        }
    }

    const int n0 = bn + tn;
    if (n0 < 4 * LHdim) {                 // guard the 2400..2431 overhang
        const int u = n0 >> 2;
        #pragma unroll
        for (int i = 0; i < 2; ++i) {
            int bb = bm + tm + i;
            const float* z = zt + (size_t)bb * (4 * LHdim) + n0;
            float gi = acc[i][0] + z[0];
            float gf = acc[i][1] + z[1];
            float gg = acc[i][2] + z[2];
            float go = acc[i][3] + z[3];
            float si = 1.f / (1.f + expf(-gi));
            float sf = 1.f / (1.f + expf(-gf));
            float so = 1.f / (1.f + expf(-go));
            float cn = sf * cin[bb * LHdim + u] + si * tanhf(gg);
            float hn = so * tanhf(cn);
            cout[bb * LHdim + u] = cn;
            hout[bb * LHdim + u] = hn;
            Hl[bb * LHdim + u]   = hn;
        }
    }
}

__global__ __launch_bounds__(256) void out_kernel(
    const float* __restrict__ x, const float* __restrict__ ow,
    const float* __restrict__ ob, float* __restrict__ out)
{
    int r    = blockIdx.x * 4 + (threadIdx.x >> 6);
    int lane = threadIdx.x & 63;
    const float* xr = x + (size_t)r * HDdim;
    float acc[NCdim];
    #pragma unroll
    for (int n = 0; n < NCdim; ++n) acc[n] = 0.f;
    for (int t = lane; t < HDdim; t += 64) {
        float xv = xr[t];
        #pragma unroll
        for (int n = 0; n < NCdim; ++n) acc[n] = fmaf(xv, ow[n * HDdim + t], acc[n]);
    }
    #pragma unroll
    for (int o = 32; o > 0; o >>= 1)
        #pragma unroll
        for (int n = 0; n < NCdim; ++n) acc[n] += __shfl_down(acc[n], o);
    if (lane == 0) {
        int b = r & 255, nn = r >> 8;
        #pragma unroll
        for (int n = 0; n < NCdim; ++n) out[((size_t)b * Ndim + nn) * NCdim + n] = acc[n] + ob[n];
    }
}

// ---------------------------------------------------------------------------
extern "C" void kernel_launch(void* const* d_in, const int* in_sizes, int n_in,
                              void* d_out, int out_size, void* d_ws, size_t ws_size,
                              hipStream_t stream)
{
    const float*  features  = (const float*)d_in[0];
    const int*    s_mask    = (const int*)  d_in[1];
    const float*  entro     = (const float*)d_in[2];
    const float*  alpha     = (const float*)d_in[3];
    const float*  threshold = (const float*)d_in[4];
    const float*  fc1_w     = (const float*)d_in[5];
    const float*  fc1_b     = (const float*)d_in[6];
    const float*  gat_w     = (const float*)d_in[7];
    const float*  gat_b     = (const float*)d_in[8];
    const float*  wr0       = (const float*)d_in[9];
    const float*  wr1       = (const float*)d_in[10];
    const float*  enhance_w = (const float*)d_in[11];
    const float*  enhance_b = (const float*)d_in[12];
    const float*  prelu_a   = (const float*)d_in[13];
    const float*  lstm_w_ih = (const float*)d_in[14];
    const float*  lstm_w_hh = (const float*)d_in[15];
    const float*  lstm_b_ih = (const float*)d_in[16];
    const float*  lstm_b_hh = (const float*)d_in[17];
    const float*  mlp_w0    = (const float*)d_in[18];
    const float*  mlp_b0    = (const float*)d_in[19];
    const float*  mlp_a0    = (const float*)d_in[20];
    const float*  mlp_w1    = (const float*)d_in[21];
    const float*  mlp_b1    = (const float*)d_in[22];
    const float*  mlp_a1    = (const float*)d_in[23];
    const float*  out_w     = (const float*)d_in[24];
    const float*  out_b     = (const float*)d_in[25];
    float* out = (float*)d_out;
    char* ws = (char*)d_ws;

    // ---- fixed workspace layout (bytes, 256-aligned) ----
    uint8_t* adj   = (uint8_t*)(ws + 0);               //  2,359,296
    float*   invn  = (float*)(ws + 2359296);
    float*   qbuf  = (float*)(ws + 2457600);
    float*   kbuf  = (float*)(ws + 2555904);
    float*   biasP = (float*)(ws + 2654208);
    float*   h0    = (float*)(ws + 2663936);
    float*   c0    = (float*)(ws + 3278336);
    float*   h1    = (float*)(ws + 3892736);
    float*   c1    = (float*)(ws + 4507136);
    float*   WhhP  = (float*)(ws + 5121536);           //  5,760,000
    u16*     WihPH = (u16*)(ws + 10881536);            //  9,494,528 (2432 x 1952, rows 2400+ zero)
    u16*     WihPL = (u16*)(ws + 20376064);
    u16*     EwH   = (u16*)(ws + 29870592);            //  2,097,152 (1024 x 1024)
    u16*     EwL   = (u16*)(ws + 31967744);
    float*   Wr2   = (float*)(ws + 34064896);          //  1,440,000 (2 x 600 x 300)
    float*   Hcat  = (float*)(ws + 35504896);          // 88,473,600 (ROWS,900) n-major
    float*   V     = (float*)(ws + 123978496);         // 58,982,400 (ROWS,600) } alias
    float*   Hlstm = V;                                //                        } Hlstm
    float*   x1    = Hcat;                             // MLP scratch (Hcat dead)
    float*   x2    = (float*)(ws + 64996096);          // Hcat + 29,491,200 B

    // ---- tier selection for chunked seq/zin region ----
    // per-chunk region: [zin | FHc,FLc alias] (T*2457600) + seqH/L (T*1998848)
    const size_t fixedNeed = 182960896ull;
    const size_t perT = 4456448ull;
    int T;
    if      (ws_size >= fixedNeed + 96ull * perT) T = 96;
    else if (ws_size >= fixedNeed + 48ull * perT) T = 48;
    else if (ws_size >= fixedNeed + 32ull * perT) T = 32;
    else if (ws_size >= fixedNeed + 16ull * perT) T = 16;
    else if (ws_size >= fixedNeed +  8ull * perT) T = 8;
    else return;                                       // visible failure, no OOB
    char* cr = ws + fixedNeed;
    u16*   FHc  = (u16*)cr;                                  // (Mc,1024) } alias
    u16*   FLc  = (u16*)(cr + (size_t)T * 1048576);          //           } zin
    float* zin  = (float*)cr;                                // (Mc,2400)
    u16*   seqH = (u16*)(cr + (size_t)T * 2457600);          // (Mc,1952)
    u16*   seqL = (u16*)(cr + (size_t)T * 2457600 + (size_t)T * 999424);

    // 1) norms + adjacency
    norm_kernel<<<ROWS / 4, 256, 0, stream>>>(features, invn);
    simadj_kernel<<<Bdim, 256, 0, stream>>>(features, invn, entro, alpha, threshold, adj);

    // 2) H0 = prelu(features @ fc1_w^T + fc1_b) -> Hcat[:, 0:300] (n-major)
    gemm_tn<1,0><<<dim3(ROWS/64, 5), 256, 0, stream>>>(
        features, Edim, 255, Ndim, 8, 1, 0,
        fc1_w, Edim, Hcat, GDdim, ROWS, HDdim, Edim, fc1_b, nullptr, prelu_a);

    // 3) GAT layers (combined V0|V1 projection, fused softmax+aggregation)
    wr_cat<<<dim3(2, 2 * Ldim * HDdim), 256, 0, stream>>>(wr0, wr1, Wr2);
    for (int l = 0; l < Ldim; ++l) {
        const float* Hsrc = Hcat + l * HDdim;
        qk_kernel<<<ROWS / 4, 256, 0, stream>>>(Hsrc, gat_w + l * 2 * HDdim, qbuf, kbuf);
        gemm_tn<0,0><<<dim3(ROWS/64, 10), 256, 0, stream>>>(
            Hsrc, GDdim, IDP, Wr2 + (size_t)l * 2 * HDdim * HDdim, HDdim,
            V, 2 * HDdim, ROWS, 2 * HDdim, HDdim, nullptr, nullptr, nullptr);
        gat_fused<<<Bdim, 256, 0, stream>>>(
            kbuf, adj, s_mask, V, Hcat + (l + 1) * HDdim);
    }

    // 4) weight conversions (bf16 hi/lo, gate-interleaved perms), state init
    split_rows<<<dim3(8, 2432), 256, 0, stream>>>(
        lstm_w_ih, Edim + GDdim, 3, LHdim, 2, 1, 0, WihPH, WihPL, 1952, 1952, 1924, 2400);
    split_rows<<<dim3(4, Edim), 256, 0, stream>>>(
        enhance_w, Edim, IDP, EwH, EwL, Edim, Edim, Edim, Edim);
    whh_perm<<<dim3(3, 4 * LHdim), 256, 0, stream>>>(lstm_w_hh, WhhP);
    bias_perm<<<10, 256, 0, stream>>>(lstm_b_ih, lstm_b_hh, biasP);
    zero_hc_kernel<<<600, 256, 0, stream>>>(h0, c0, Bdim * LHdim);

    // 5) chunked: feat split -> enhance MFMA -> Hcat split -> zin MFMA -> LSTM
    float* hb[2] = {h0, h1};
    float* cb[2] = {c0, c1};
    int cur = 0;
    for (int t0 = 0; t0 < Ndim; t0 += T) {
        int Mc = T * Bdim;
        split_rows<<<dim3(4, Mc), 256, 0, stream>>>(
            features, Edim, 255, Ndim, 8, 1, t0, FHc, FLc, Edim, Edim, Edim, Mc);
        gemm_mfma3<1,1><<<dim3(Mc/128, 8), 256, 0, stream>>>(
            FHc, FLc, Edim, EwH, EwL, Edim,
            nullptr, seqH, seqL, 1952, Mc, Edim, Edim, enhance_b, prelu_a);
        split_rows<<<dim3(4, Mc), 256, 0, stream>>>(
            Hcat, GDdim, 0x7FFFFFFF, 1, 30, 0, t0 * Bdim,
            seqH + 1024, seqL + 1024, 1952, 928, GDdim, Mc);
        gemm_mfma3<0,0><<<dim3(Mc/128, 19), 256, 0, stream>>>(
            seqH, seqL, 1952, WihPH, WihPL, 1952,
            zin, nullptr, nullptr, 4 * LHdim, Mc, 4 * LHdim, 1952, biasP, nullptr);
        for (int tl = 0; tl < T; ++tl) {
            lstm_step3<<<dim3(8, 38), 256, 0, stream>>>(
                hb[cur], cb[cur], WhhP, zin + (size_t)tl * Bdim * 4 * LHdim,
                hb[cur ^ 1], cb[cur ^ 1],
                Hlstm + (size_t)(t0 + tl) * Bdim * LHdim);
            cur ^= 1;
        }
    }

    // 6) MLP head + output
    gemm_tn<1,0><<<dim3(ROWS/64, 5), 256, 0, stream>>>(
        Hlstm, LHdim, IDP, mlp_w0, LHdim, x1, HDdim, ROWS, HDdim, LHdim, mlp_b0, nullptr, mlp_a0);
    gemm_tn<1,0><<<dim3(ROWS/64, 5), 256, 0, stream>>>(
        x1, HDdim, IDP, mlp_w1, HDdim, x2, HDdim, ROWS, HDdim, HDdim, mlp_b1, nullptr, mlp_a1);
    out_kernel<<<ROWS / 4, 256, 0, stream>>>(x2, out_w, out_b, out);
}

// Round 8
// 4453.566 us; speedup vs baseline: 2.3805x; 1.7796x over previous
//
#include <hip/hip_runtime.h>
#include <cstdint>
#include <cstddef>

#define Bdim 256
#define Ndim 96
#define Edim 1024
#define HDdim 300
#define Ldim 2
#define LHdim 600
#define NCdim 7
#define GDdim 900              // HD*(L+1)
#define ROWS (Bdim*Ndim)       // 24576

typedef unsigned short u16;
typedef float f32x4 __attribute__((ext_vector_type(4)));
typedef short bf16x8 __attribute__((ext_vector_type(8)));

// Identity row-perm constants
#define IDP 0x7FFFFFFF, 1, 30, 0, 0

__device__ inline u16 f2bf(float x) {
    unsigned int u = __builtin_bit_cast(unsigned int, x);
    unsigned int r = (u + 0x7fffu + ((u >> 16) & 1u)) >> 16;   // RNE
    return (u16)r;
}
__device__ inline float bf2f(u16 h) {
    unsigned int u = ((unsigned int)h) << 16;
    return __builtin_bit_cast(float, u);
}

// ---------------------------------------------------------------------------
// fp32 GEMM (fc1 / GAT V / MLP): C[m,n]=act(sum_k A[rowA(m),k]W[n,k]+b)
// ---------------------------------------------------------------------------
template<int ACT, int ACC>
__global__ __launch_bounds__(256) void gemm_tn(
    const float* __restrict__ A, int lda,
    int pmask, int pmul1, int pshift, int pmul2, int padd,
    const float* __restrict__ W, int ldw,
    float* __restrict__ C, int ldc,
    int M, int Nd, int K,
    const float* __restrict__ bias1,
    const float* __restrict__ bias2,
    const float* __restrict__ aptr)
{
    __shared__ __align__(16) float As[16][68];
    __shared__ __align__(16) float Ws[16][68];
    const int bm = blockIdx.x * 64;
    const int bn = blockIdx.y * 64;
    const int tid = threadIdx.x;
    const int lm  = tid & 63;
    const int lk4 = (tid >> 6) << 2;
    const int tm = (tid >> 4) << 2;
    const int tn = (tid & 15) << 2;
    float acc[4][4] = {{0.f,0.f,0.f,0.f},{0.f,0.f,0.f,0.f},{0.f,0.f,0.f,0.f},{0.f,0.f,0.f,0.f}};
    const int am = bm + lm;
    const int wn = bn + lm;
    const int rowA = (am & pmask) * pmul1 + (am >> pshift) * pmul2 + padd;

    for (int k0 = 0; k0 < K; k0 += 16) {
        float4 av, wv;
        const bool fullk = (k0 + 16 <= K);
        if (fullk) {
            av = (am < M)  ? *(const float4*)(A + (size_t)rowA * lda + k0 + lk4) : make_float4(0.f,0.f,0.f,0.f);
            wv = (wn < Nd) ? *(const float4*)(W + (size_t)wn   * ldw + k0 + lk4) : make_float4(0.f,0.f,0.f,0.f);
        } else {
            float ta[4], tw[4];
            #pragma unroll
            for (int u = 0; u < 4; ++u) {
                int k = k0 + lk4 + u;
                ta[u] = (am < M  && k < K) ? A[(size_t)rowA * lda + k] : 0.f;
                tw[u] = (wn < Nd && k < K) ? W[(size_t)wn   * ldw + k] : 0.f;
            }
            av = make_float4(ta[0],ta[1],ta[2],ta[3]);
            wv = make_float4(tw[0],tw[1],tw[2],tw[3]);
        }
        __syncthreads();
        As[lk4+0][lm] = av.x; As[lk4+1][lm] = av.y; As[lk4+2][lm] = av.z; As[lk4+3][lm] = av.w;
        Ws[lk4+0][lm] = wv.x; Ws[lk4+1][lm] = wv.y; Ws[lk4+2][lm] = wv.z; Ws[lk4+3][lm] = wv.w;
        __syncthreads();
        #pragma unroll
        for (int kk = 0; kk < 16; ++kk) {
            float a0[4], w0[4];
            *(float4*)a0 = *(const float4*)&As[kk][tm];
            *(float4*)w0 = *(const float4*)&Ws[kk][tn];
            #pragma unroll
            for (int i = 0; i < 4; ++i)
                #pragma unroll
                for (int j = 0; j < 4; ++j)
                    acc[i][j] = fmaf(a0[i], w0[j], acc[i][j]);
        }
    }

    const float aval = (ACT == 1) ? *aptr : 0.f;
    #pragma unroll
    for (int i = 0; i < 4; ++i) {
        int m = bm + tm + i;
        if (m >= M) continue;
        #pragma unroll
        for (int j = 0; j < 4; ++j) {
            int n = bn + tn + j;
            if (n >= Nd) continue;
            float v = acc[i][j];
            if (bias1) v += bias1[n];
            if (bias2) v += bias2[n];
            if (ACC)   v += C[(size_t)m * ldc + n];
            if (ACT == 1) v = (v >= 0.f) ? v : aval * v;
            C[(size_t)m * ldc + n] = v;
        }
    }
}

// ---------------------------------------------------------------------------
// bf16x3 split MFMA GEMM (proven reg->LDS staging) + bijective XCD swizzle.
// C = act(sum_k (Ah+Al)[m,k]*(Wh+Wl)[n,k] + bias). K mult of 32; lda/ldw mult 8.
// OUT: 0 -> fp32 C; 1 -> split bf16 (Ch,Cl). ACT: 1 -> prelu(aptr).
// Tile 128x128, BK=32, 4 waves (2x2), wave tile 64x64 = 4x4 frags of 16x16x32.
// ---------------------------------------------------------------------------
template<int OUT, int ACT>
__global__ __launch_bounds__(256) void gemm_mfma3(
    const u16* __restrict__ Ah, const u16* __restrict__ Al, int lda,
    const u16* __restrict__ Wh, const u16* __restrict__ Wl, int ldw,
    float* __restrict__ C, u16* __restrict__ Ch, u16* __restrict__ Cl, int ldc,
    int M, int Nd, int K,
    const float* __restrict__ bias, const float* __restrict__ aptr)
{
    __shared__ u16 AtH[4][1024];
    __shared__ u16 AtL[4][1024];
    __shared__ u16 WtH[4][1024];
    __shared__ u16 WtL[4][1024];
    const int tid  = threadIdx.x;
    // bijective XCD swizzle (m204): consecutive-on-XCD blocks share B panel
    const int nx = gridDim.x;
    const int nwg = nx * gridDim.y;
    const int lin = blockIdx.y * nx + blockIdx.x;
    const int q = nwg >> 3, r8 = nwg & 7;
    const int xcd = lin & 7, off = lin >> 3;
    const int swz = (xcd < r8) ? xcd * (q + 1) + off
                               : r8 * (q + 1) + (xcd - r8) * q + off;
    const int bm   = (swz % nx) * 128;
    const int bn   = (swz / nx) * 128;
    const int wv   = tid >> 6;
    const int lane = tid & 63;
    const int wr   = (wv >> 1) * 64;
    const int wc   = (wv & 1) * 64;
    const int l15  = lane & 15;
    const int kseg = lane >> 4;

    f32x4 acc[4][4];
    #pragma unroll
    for (int i = 0; i < 4; ++i)
        #pragma unroll
        for (int j = 0; j < 4; ++j) acc[i][j] = (f32x4){0.f,0.f,0.f,0.f};

    const int srow = tid & 127;
    const bool isA = (tid < 128);
    const int gr   = isA ? (bm + srow) : (bn + srow);
    const int glim = isA ? M : Nd;
    const u16* pHbase = (isA ? Ah : Wh) + (size_t)gr * (isA ? lda : ldw);
    const u16* pLbase = (isA ? Al : Wl) + (size_t)gr * (isA ? lda : ldw);
    u16* dH = isA ? &AtH[0][0] : &WtH[0][0];
    u16* dL = isA ? &AtL[0][0] : &WtL[0][0];

    for (int k0 = 0; k0 < K; k0 += 32) {
        __syncthreads();
        {
            const bool ok = (gr < glim);
            #pragma unroll
            for (int s = 0; s < 4; ++s) {
                bf16x8 vH = {0,0,0,0,0,0,0,0};
                bf16x8 vL = {0,0,0,0,0,0,0,0};
                if (ok) {
                    vH = *(const bf16x8*)(pHbase + k0 + s * 8);
                    vL = *(const bf16x8*)(pLbase + k0 + s * 8);
                }
                *(bf16x8*)(dH + s * 1024 + srow * 8) = vH;
                *(bf16x8*)(dL + s * 1024 + srow * 8) = vL;
            }
        }
        __syncthreads();
        bf16x8 aH[4], aL[4], bH[4], bL[4];
        #pragma unroll
        for (int f = 0; f < 4; ++f) {
            int ar = wr + f * 16 + l15;
            int br = wc + f * 16 + l15;
            aH[f] = *(const bf16x8*)&AtH[kseg][ar * 8];
            aL[f] = *(const bf16x8*)&AtL[kseg][ar * 8];
            bH[f] = *(const bf16x8*)&WtH[kseg][br * 8];
            bL[f] = *(const bf16x8*)&WtL[kseg][br * 8];
        }
        #pragma unroll
        for (int i = 0; i < 4; ++i)
            #pragma unroll
            for (int j = 0; j < 4; ++j)
                acc[i][j] = __builtin_amdgcn_mfma_f32_16x16x32_bf16(aH[i], bH[j], acc[i][j], 0, 0, 0);
        #pragma unroll
        for (int i = 0; i < 4; ++i)
            #pragma unroll
            for (int j = 0; j < 4; ++j)
                acc[i][j] = __builtin_amdgcn_mfma_f32_16x16x32_bf16(aH[i], bL[j], acc[i][j], 0, 0, 0);
        #pragma unroll
        for (int i = 0; i < 4; ++i)
            #pragma unroll
            for (int j = 0; j < 4; ++j)
                acc[i][j] = __builtin_amdgcn_mfma_f32_16x16x32_bf16(aL[i], bH[j], acc[i][j], 0, 0, 0);
    }

    const float av = (ACT == 1) ? *aptr : 0.f;
    const int r4 = (lane >> 4) * 4;
    #pragma unroll
    for (int j = 0; j < 4; ++j) {
        int col = bn + wc + j * 16 + l15;
        if (col >= Nd) continue;
        float bv = bias ? bias[col] : 0.f;
        #pragma unroll
        for (int i = 0; i < 4; ++i) {
            #pragma unroll
            for (int rr = 0; rr < 4; ++rr) {
                int row = bm + wr + i * 16 + r4 + rr;
                if (row >= M) continue;
                float v = acc[i][j][rr] + bv;
                if (ACT == 1) v = (v >= 0.f) ? v : av * v;
                if (OUT == 0) {
                    C[(size_t)row * ldc + col] = v;
                } else {
                    u16 h = f2bf(v);
                    Ch[(size_t)row * ldc + col] = h;
                    Cl[(size_t)row * ldc + col] = f2bf(v - bf2f(h));
                }
            }
        }
    }
}

// ---------------------------------------------------------------------------
// split fp32 -> bf16 hi/lo, vectorized: 4 rows/block, 8 cols/thread.
// rows must be a multiple of 4; wcols a multiple of 8.
// ---------------------------------------------------------------------------
__global__ __launch_bounds__(256) void split_rows8(
    const float* __restrict__ src, int srcld,
    int pmask, int pmul1, int pshift, int pmul2, int padd,
    u16* __restrict__ dstH, u16* __restrict__ dstL, int dstld,
    int wcols, int validK, int validRows)
{
    const int r = blockIdx.y * 4 + (threadIdx.x >> 6);
    const int c = (blockIdx.x * 64 + (threadIdx.x & 63)) * 8;
    if (c >= wcols) return;
    const int sr = (r & pmask) * pmul1 + (r >> pshift) * pmul2 + padd;
    const float* s = src + (size_t)sr * srcld;
    const bool rok = (r < validRows);
    float v[8];
    if (rok && c + 8 <= validK) {
        *(float4*)&v[0] = *(const float4*)(s + c);
        *(float4*)&v[4] = *(const float4*)(s + c + 4);
    } else {
        #pragma unroll
        for (int u = 0; u < 8; ++u) v[u] = (rok && c + u < validK) ? s[c + u] : 0.f;
    }
    bf16x8 H8, L8;
    #pragma unroll
    for (int u = 0; u < 8; ++u) {
        u16 h = f2bf(v[u]);
        H8[u] = (short)h;
        L8[u] = (short)f2bf(v[u] - bf2f(h));
    }
    *(bf16x8*)(dstH + (size_t)r * dstld + c) = H8;
    *(bf16x8*)(dstL + (size_t)r * dstld + c) = L8;
}

// biasP[n'] = b_ih[orig]+b_hh[orig], orig = (n'&3)*600+(n'>>2)
__global__ __launch_bounds__(256) void bias_perm(
    const float* __restrict__ bih, const float* __restrict__ bhh, float* __restrict__ dst)
{
    int n = blockIdx.x * 256 + threadIdx.x;
    if (n >= 4 * LHdim) return;
    int o = (n & 3) * LHdim + (n >> 2);
    dst[n] = bih[o] + bhh[o];
}

// Wr2[l][r][c]: r<300 -> wr0[l][r][c], else wr1[l][r-300][c]
__global__ __launch_bounds__(256) void wr_cat(
    const float* __restrict__ wr0, const float* __restrict__ wr1, float* __restrict__ dst)
{
    int c = blockIdx.x * 256 + threadIdx.x;
    if (c >= HDdim) return;
    int lr = blockIdx.y;
    int l = lr / (2 * HDdim), r = lr % (2 * HDdim);
    const float* src = (r < HDdim)
        ? wr0 + ((size_t)l * HDdim + r) * HDdim
        : wr1 + ((size_t)l * HDdim + (r - HDdim)) * HDdim;
    dst[(size_t)lr * HDdim + c] = src[c];
}

__global__ __launch_bounds__(256) void zero_range(float* __restrict__ p, int n)
{
    int i = blockIdx.x * 256 + threadIdx.x;
    if (i < n) p[i] = 0.f;
}

// ---------------------------------------------------------------------------
__global__ __launch_bounds__(256) void norm_kernel(const float* __restrict__ f, float* __restrict__ invn)
{
    int row  = blockIdx.x * 4 + (threadIdx.x >> 6);
    int lane = threadIdx.x & 63;
    const float* fr = f + (size_t)row * Edim;
    float ss = 0.f;
    for (int t = lane; t < Edim; t += 64) { float v = fr[t]; ss = fmaf(v, v, ss); }
    #pragma unroll
    for (int o = 32; o > 0; o >>= 1) ss += __shfl_down(ss, o);
    if (lane == 0) invn[row] = 1.f / (sqrtf(ss) + 1e-8f);
}

__global__ __launch_bounds__(256) void simadj_kernel(
    const float* __restrict__ f, const float* __restrict__ invn,
    const float* __restrict__ entro, const float* __restrict__ alphap,
    const float* __restrict__ thrp, uint8_t* __restrict__ adj)
{
    int b = blockIdx.x;
    __shared__ float S[16][100];
    int tid = threadIdx.x;
    int i0 = (tid >> 4) * 6, j0 = (tid & 15) * 6;
    float acc[6][6];
    #pragma unroll
    for (int i = 0; i < 6; ++i)
        #pragma unroll
        for (int j = 0; j < 6; ++j) acc[i][j] = 0.f;
    const float* fb = f + (size_t)b * Ndim * Edim;

    for (int k0 = 0; k0 < Edim; k0 += 16) {
        __syncthreads();
        #pragma unroll
        for (int r = 0; r < 6; ++r) {
            int n = (tid >> 4) + r * 16;
            S[tid & 15][n] = fb[(size_t)n * Edim + k0 + (tid & 15)];
        }
        __syncthreads();
        #pragma unroll
        for (int kk = 0; kk < 16; ++kk) {
            float a[6], bb[6];
            #pragma unroll
            for (int u = 0; u < 6; ++u) a[u] = S[kk][i0 + u];
            #pragma unroll
            for (int u = 0; u < 6; ++u) bb[u] = S[kk][j0 + u];
            #pragma unroll
            for (int i = 0; i < 6; ++i)
                #pragma unroll
                for (int j = 0; j < 6; ++j)
                    acc[i][j] = fmaf(a[i], bb[j], acc[i][j]);
        }
    }

    float alpha = *alphap, thr = *thrp;
    float onem = 1.f - alpha;
    #pragma unroll
    for (int i = 0; i < 6; ++i) {
        int ii = i0 + i;
        float inv_i = invn[b * Ndim + ii];
        #pragma unroll
        for (int j = 0; j < 6; ++j) {
            int jj = j0 + j;
            float simv = acc[i][j] * inv_i * invn[b * Ndim + jj];
            float comb = alpha * entro[b * Ndim + jj] + onem * simv;
            adj[((size_t)b * Ndim + ii) * Ndim + jj] = (comb > thr) ? 1 : 0;
        }
    }
}

__global__ __launch_bounds__(256) void qk_kernel(
    const float* __restrict__ Hsrc, const float* __restrict__ wqk,
    float* __restrict__ q, float* __restrict__ k)
{
    int row  = blockIdx.x * 4 + (threadIdx.x >> 6);
    int lane = threadIdx.x & 63;
    const float* h = Hsrc + (size_t)row * GDdim;
    float sq = 0.f, sk = 0.f;
    for (int t = lane; t < HDdim; t += 64) {
        float hv = h[t];
        sq = fmaf(hv, wqk[t], sq);
        sk = fmaf(hv, wqk[HDdim + t], sk);
    }
    #pragma unroll
    for (int o = 32; o > 0; o >>= 1) { sq += __shfl_down(sq, o); sk += __shfl_down(sk, o); }
    if (lane == 0) { q[row] = sq; k[row] = sk; }
}

// ---------------------------------------------------------------------------
// Fused GAT attention for one batch b (q, gat_b cancel in softmax).
// V combined: cols 0..299 = V0, 300..599 = V1, row stride 600 (n-major rows).
// ---------------------------------------------------------------------------
__global__ __launch_bounds__(256) void gat_fused(
    const float* __restrict__ kbuf, const uint8_t* __restrict__ adj,
    const int* __restrict__ smask,
    const float* __restrict__ V,
    float* __restrict__ Mout)
{
    __shared__ float P0[96][98];
    __shared__ float P1[96][98];
    __shared__ float Vs0[96][96];
    __shared__ float Vs1[96][96];
    __shared__ float ek[96];
    __shared__ float rden[96];
    __shared__ float red[256];
    const int b = blockIdx.x;
    const int tid = threadIdx.x;

    float kj = (tid < Ndim) ? kbuf[tid * Bdim + b] : -1e30f;
    red[tid] = kj;
    __syncthreads();
    #pragma unroll
    for (int s = 128; s > 0; s >>= 1) {
        if (tid < s) red[tid] = fmaxf(red[tid], red[tid + s]);
        __syncthreads();
    }
    float kmax = red[0];
    if (tid < Ndim) ek[tid] = expf(kj - kmax);
    __syncthreads();
    if (tid < Ndim) {
        const uint8_t* ar = adj + ((size_t)b * Ndim + tid) * Ndim;
        float s = 0.f;
        for (int j = 0; j < Ndim; ++j) if (ar[j]) s += ek[j];
        rden[tid] = 1.f / s;   // diagonal always allowed -> s > 0
    }
    __syncthreads();
    for (int idx = tid; idx < Ndim * Ndim; idx += 256) {
        int i = idx / Ndim, j = idx - i * Ndim;
        float a = adj[((size_t)b * Ndim + i) * Ndim + j] ? ek[j] * rden[i] : 0.f;
        int s = smask[((size_t)b * Ndim + i) * Ndim + j];
        P0[i][j] = s ? a : 0.f;
        P1[i][j] = s ? 0.f : a;
    }
    __syncthreads();

    const int ti = tid >> 4, td = tid & 15;
    const int i0 = ti * 6, dbase = td * 6;
    for (int p = 0; p < 4; ++p) {
        const int d0 = p * 96;
        const int dw = (p == 3) ? (HDdim - 288) : 96;
        for (int idx = tid; idx < 96 * 24; idx += 256) {
            int j = idx / 24, q4 = (idx - j * 24) * 4;
            if (q4 < dw) {
                size_t g = ((size_t)(j * Bdim + b)) * (2 * HDdim) + d0 + q4;
                *(float4*)&Vs0[j][q4] = *(const float4*)(V + g);
                *(float4*)&Vs1[j][q4] = *(const float4*)(V + g + HDdim);
            }
        }
        __syncthreads();
        float acc[6][6];
        #pragma unroll
        for (int ii = 0; ii < 6; ++ii)
            #pragma unroll
            for (int dd = 0; dd < 6; ++dd) acc[ii][dd] = 0.f;
        for (int j = 0; j < Ndim; j += 2) {
            float2 pa[6], pb[6];
            #pragma unroll
            for (int ii = 0; ii < 6; ++ii) {
                pa[ii] = *(const float2*)&P0[i0 + ii][j];
                pb[ii] = *(const float2*)&P1[i0 + ii][j];
            }
            float2 v0a[3], v0b[3], v1a[3], v1b[3];
            #pragma unroll
            for (int dd = 0; dd < 3; ++dd) {
                v0a[dd] = *(const float2*)&Vs0[j][dbase + 2 * dd];
                v0b[dd] = *(const float2*)&Vs0[j + 1][dbase + 2 * dd];
                v1a[dd] = *(const float2*)&Vs1[j][dbase + 2 * dd];
                v1b[dd] = *(const float2*)&Vs1[j + 1][dbase + 2 * dd];
            }
            #pragma unroll
            for (int ii = 0; ii < 6; ++ii)
                #pragma unroll
                for (int dd = 0; dd < 3; ++dd) {
                    acc[ii][2*dd]   += pa[ii].x * v0a[dd].x + pb[ii].x * v1a[dd].x
                                     + pa[ii].y * v0b[dd].x + pb[ii].y * v1b[dd].x;
                    acc[ii][2*dd+1] += pa[ii].x * v0a[dd].y + pb[ii].x * v1a[dd].y
                                     + pa[ii].y * v0b[dd].y + pb[ii].y * v1b[dd].y;
                }
        }
        __syncthreads();
        #pragma unroll
        for (int ii = 0; ii < 6; ++ii) {
            #pragma unroll
            for (int dd = 0; dd < 6; ++dd) {
                int d = dbase + dd;
                if (d < dw)
                    Mout[((size_t)((i0 + ii) * Bdim + b)) * GDdim + d0 + d] = acc[ii][dd];
            }
        }
    }
}

// ---------------------------------------------------------------------------
// LSTM step via bf16x3 MFMA. h kept split-bf16 (256 x 608, k-pad zeroed).
// W = WhhP split bf16 (2432 x 608, gate-interleaved rows, pad rows/cols zero).
// Tile 32 batch x 64 gate-cols, grid (8,38). Gates -> LDS -> fused cell.
// ---------------------------------------------------------------------------
__global__ __launch_bounds__(256) void lstm_mfma(
    const u16* __restrict__ hH, const u16* __restrict__ hL,
    const float* __restrict__ cin,
    const u16* __restrict__ WH, const u16* __restrict__ WL,
    const float* __restrict__ zt,
    u16* __restrict__ hHo, u16* __restrict__ hLo,
    float* __restrict__ cout, float* __restrict__ Hl)
{
    __shared__ u16 AsH[4][256];
    __shared__ u16 AsL[4][256];
    __shared__ u16 WsH[4][512];
    __shared__ u16 WsL[4][512];
    __shared__ __align__(16) float gates[32][68];
    const int tid = threadIdx.x;
    const int bm = blockIdx.x * 32;
    const int bn = blockIdx.y * 64;
    const int wv = tid >> 6;
    const int lane = tid & 63;
    const int l15 = lane & 15;
    const int kseg = lane >> 4;

    // A staging: tid<128 -> AsH vec tid, else AsL vec tid-128
    const int av = tid & 127;
    const int arow = av >> 2, akc = av & 3;            // kc chunk (x8)
    const u16* asrc = ((tid < 128) ? hH : hL) + (size_t)(bm + arow) * 608 + akc * 8;
    u16* adst = ((tid < 128) ? &AsH[0][0] : &AsL[0][0]) + akc * 256 + arow * 8;
    // W staging: each thread one vec of WsH and WsL
    const int wrow = tid >> 2, wkc = tid & 3;
    const u16* wsrcH = WH + (size_t)(bn + wrow) * 608 + wkc * 8;
    const u16* wsrcL = WL + (size_t)(bn + wrow) * 608 + wkc * 8;
    u16* wdstH = &WsH[wkc][wrow * 8];
    u16* wdstL = &WsL[wkc][wrow * 8];

    f32x4 acc[2];
    acc[0] = (f32x4){0.f,0.f,0.f,0.f};
    acc[1] = (f32x4){0.f,0.f,0.f,0.f};

    for (int k0 = 0; k0 < 608; k0 += 32) {
        __syncthreads();
        *(bf16x8*)adst  = *(const bf16x8*)(asrc + k0);
        *(bf16x8*)wdstH = *(const bf16x8*)(wsrcH + k0);
        *(bf16x8*)wdstL = *(const bf16x8*)(wsrcL + k0);
        __syncthreads();
        bf16x8 aH[2], aL[2], bH, bL;
        #pragma unroll
        for (int i = 0; i < 2; ++i) {
            int ar = i * 16 + l15;
            aH[i] = *(const bf16x8*)&AsH[kseg][ar * 8];
            aL[i] = *(const bf16x8*)&AsL[kseg][ar * 8];
        }
        {
            int br = wv * 16 + l15;
            bH = *(const bf16x8*)&WsH[kseg][br * 8];
            bL = *(const bf16x8*)&WsL[kseg][br * 8];
        }
        #pragma unroll
        for (int i = 0; i < 2; ++i) {
            acc[i] = __builtin_amdgcn_mfma_f32_16x16x32_bf16(aH[i], bH, acc[i], 0, 0, 0);
            acc[i] = __builtin_amdgcn_mfma_f32_16x16x32_bf16(aH[i], bL, acc[i], 0, 0, 0);
            acc[i] = __builtin_amdgcn_mfma_f32_16x16x32_bf16(aL[i], bH, acc[i], 0, 0, 0);
        }
    }

    // gates to LDS: row = i*16 + (lane>>4)*4 + rr, col = wv*16 + l15
    const int r4 = (lane >> 4) * 4;
    __syncthreads();
    #pragma unroll
    for (int i = 0; i < 2; ++i)
        #pragma unroll
        for (int rr = 0; rr < 4; ++rr)
            gates[i * 16 + r4 + rr][wv * 16 + l15] = acc[i][rr];
    __syncthreads();

    // fused cell: 512 cells (32 batches x 16 u), 2 per thread
    #pragma unroll
    for (int s = 0; s < 2; ++s) {
        int cell = tid + s * 256;
        int row = cell >> 4;          // 0..31
        int ui  = cell & 15;          // 0..15
        int n0  = bn + ui * 4;
        int u   = n0 >> 2;
        if (u < LHdim) {
            int bb = bm + row;
            float4 g = *(const float4*)&gates[row][ui * 4];
            const float* z = zt + (size_t)bb * (4 * LHdim) + n0;
            float gi = g.x + z[0];
            float gf = g.y + z[1];
            float gg = g.z + z[2];
            float go = g.w + z[3];
            float si = 1.f / (1.f + expf(-gi));
            float sf = 1.f / (1.f + expf(-gf));
            float so = 1.f / (1.f + expf(-go));
            float cn = sf * cin[bb * LHdim + u] + si * tanhf(gg);
            float hn = so * tanhf(cn);
            cout[bb * LHdim + u] = cn;
            Hl[bb * LHdim + u]   = hn;
            u16 hh = f2bf(hn);
            hHo[(size_t)bb * 608 + u] = hh;
            hLo[(size_t)bb * 608 + u] = f2bf(hn - bf2f(hh));
        }
    }
}

__global__ __launch_bounds__(256) void out_kernel(
    const float* __restrict__ x, const float* __restrict__ ow,
    const float* __restrict__ ob, float* __restrict__ out)
{
    int r    = blockIdx.x * 4 + (threadIdx.x >> 6);
    int lane = threadIdx.x & 63;
    const float* xr = x + (size_t)r * HDdim;
    float acc[NCdim];
    #pragma unroll
    for (int n = 0; n < NCdim; ++n) acc[n] = 0.f;
    for (int t = lane; t < HDdim; t += 64) {
        float xv = xr[t];
        #pragma unroll
        for (int n = 0; n < NCdim; ++n) acc[n] = fmaf(xv, ow[n * HDdim + t], acc[n]);
    }
    #pragma unroll
    for (int o = 32; o > 0; o >>= 1)
        #pragma unroll
        for (int n = 0; n < NCdim; ++n) acc[n] += __shfl_down(acc[n], o);
    if (lane == 0) {
        int b = r & 255, nn = r >> 8;
        #pragma unroll
        for (int n = 0; n < NCdim; ++n) out[((size_t)b * Ndim + nn) * NCdim + n] = acc[n] + ob[n];
    }
}

// ---------------------------------------------------------------------------
extern "C" void kernel_launch(void* const* d_in, const int* in_sizes, int n_in,
                              void* d_out, int out_size, void* d_ws, size_t ws_size,
                              hipStream_t stream)
{
    const float*  features  = (const float*)d_in[0];
    const int*    s_mask    = (const int*)  d_in[1];
    const float*  entro     = (const float*)d_in[2];
    const float*  alpha     = (const float*)d_in[3];
    const float*  threshold = (const float*)d_in[4];
    const float*  fc1_w     = (const float*)d_in[5];
    const float*  fc1_b     = (const float*)d_in[6];
    const float*  gat_w     = (const float*)d_in[7];
    const float*  gat_b     = (const float*)d_in[8];
    const float*  wr0       = (const float*)d_in[9];
    const float*  wr1       = (const float*)d_in[10];
    const float*  enhance_w = (const float*)d_in[11];
    const float*  enhance_b = (const float*)d_in[12];
    const float*  prelu_a   = (const float*)d_in[13];
    const float*  lstm_w_ih = (const float*)d_in[14];
    const float*  lstm_w_hh = (const float*)d_in[15];
    const float*  lstm_b_ih = (const float*)d_in[16];
    const float*  lstm_b_hh = (const float*)d_in[17];
    const float*  mlp_w0    = (const float*)d_in[18];
    const float*  mlp_b0    = (const float*)d_in[19];
    const float*  mlp_a0    = (const float*)d_in[20];
    const float*  mlp_w1    = (const float*)d_in[21];
    const float*  mlp_b1    = (const float*)d_in[22];
    const float*  mlp_a1    = (const float*)d_in[23];
    const float*  out_w     = (const float*)d_in[24];
    const float*  out_b     = (const float*)d_in[25];
    float* out = (float*)d_out;
    char* ws = (char*)d_ws;

    // ---- fixed workspace layout (bytes, 256-aligned) ----
    uint8_t* adj   = (uint8_t*)(ws + 0);               //  2,359,296
    float*   invn  = (float*)(ws + 2359296);
    float*   qbuf  = (float*)(ws + 2457600);
    float*   kbuf  = (float*)(ws + 2555904);
    float*   biasP = (float*)(ws + 2654208);           //      9,728
    float*   c0    = (float*)(ws + 2663936);           //    614,400
    float*   c1    = (float*)(ws + 3278336);           //    614,400
    u16*     hH0   = (u16*)(ws + 3892736);             //    311,296 (256 x 608)
    u16*     hL0   = (u16*)(ws + 4204032);
    u16*     hH1   = (u16*)(ws + 4515328);
    u16*     hL1   = (u16*)(ws + 4826624);
    u16*     WhhPH = (u16*)(ws + 5137920);             //  2,957,312 (2432 x 608)
    u16*     WhhPL = (u16*)(ws + 8095232);
    u16*     WihPH = (u16*)(ws + 11052544);            //  9,494,528 (2432 x 1952)
    u16*     WihPL = (u16*)(ws + 20547072);
    u16*     EwH   = (u16*)(ws + 30041600);            //  2,097,152 (1024 x 1024)
    u16*     EwL   = (u16*)(ws + 32138752);
    float*   Wr2   = (float*)(ws + 34235904);          //  1,440,256 (2 x 600 x 300)
    float*   Hcat  = (float*)(ws + 35676160);          // 88,473,600 (ROWS,900) n-major
    float*   V     = (float*)(ws + 124149760);         // 58,982,400 (ROWS,600) } alias
    float*   Hlstm = V;                                //                        } Hlstm
    float*   x1    = Hcat;                             // MLP scratch (Hcat dead)
    float*   x2    = (float*)(ws + 65167360);          // Hcat + 29,491,200 B

    // ---- tier selection for chunked seq/zin region ----
    const size_t fixedNeed = 183132160ull;
    const size_t perT = 4456448ull;
    int T;
    if      (ws_size >= fixedNeed + 96ull * perT) T = 96;
    else if (ws_size >= fixedNeed + 48ull * perT) T = 48;
    else if (ws_size >= fixedNeed + 32ull * perT) T = 32;
    else if (ws_size >= fixedNeed + 16ull * perT) T = 16;
    else if (ws_size >= fixedNeed +  8ull * perT) T = 8;
    else return;                                       // visible failure, no OOB
    char* cr = ws + fixedNeed;
    u16*   FHc  = (u16*)cr;                                  // (Mc,1024) } alias
    u16*   FLc  = (u16*)(cr + (size_t)T * 1048576);          //           } zin
    float* zin  = (float*)cr;                                // (Mc,2400)
    u16*   seqH = (u16*)(cr + (size_t)T * 2457600);          // (Mc,1952)
    u16*   seqL = (u16*)(cr + (size_t)T * 2457600 + (size_t)T * 999424);

    // 1) norms + adjacency
    norm_kernel<<<ROWS / 4, 256, 0, stream>>>(features, invn);
    simadj_kernel<<<Bdim, 256, 0, stream>>>(features, invn, entro, alpha, threshold, adj);

    // 2) H0 = prelu(features @ fc1_w^T + fc1_b) -> Hcat[:, 0:300] (n-major)
    gemm_tn<1,0><<<dim3(ROWS/64, 5), 256, 0, stream>>>(
        features, Edim, 255, Ndim, 8, 1, 0,
        fc1_w, Edim, Hcat, GDdim, ROWS, HDdim, Edim, fc1_b, nullptr, prelu_a);

    // 3) GAT layers (combined V0|V1 projection, fused softmax+aggregation)
    wr_cat<<<dim3(2, 2 * Ldim * HDdim), 256, 0, stream>>>(wr0, wr1, Wr2);
    for (int l = 0; l < Ldim; ++l) {
        const float* Hsrc = Hcat + l * HDdim;
        qk_kernel<<<ROWS / 4, 256, 0, stream>>>(Hsrc, gat_w + l * 2 * HDdim, qbuf, kbuf);
        gemm_tn<0,0><<<dim3(ROWS/64, 10), 256, 0, stream>>>(
            Hsrc, GDdim, IDP, Wr2 + (size_t)l * 2 * HDdim * HDdim, HDdim,
            V, 2 * HDdim, ROWS, 2 * HDdim, HDdim, nullptr, nullptr, nullptr);
        gat_fused<<<Bdim, 256, 0, stream>>>(
            kbuf, adj, s_mask, V, Hcat + (l + 1) * HDdim);
    }

    // 4) weight conversions (bf16 hi/lo, gate-interleaved perms), state init
    split_rows8<<<dim3(4, 608), 256, 0, stream>>>(
        lstm_w_ih, Edim + GDdim, 3, LHdim, 2, 1, 0, WihPH, WihPL, 1952, 1952, 1924, 2400);
    split_rows8<<<dim3(2, 256), 256, 0, stream>>>(
        enhance_w, Edim, IDP, EwH, EwL, Edim, Edim, Edim, Edim);
    split_rows8<<<dim3(2, 608), 256, 0, stream>>>(
        lstm_w_hh, LHdim, 3, LHdim, 2, 1, 0, WhhPH, WhhPL, 608, 608, LHdim, 2400);
    bias_perm<<<10, 256, 0, stream>>>(lstm_b_ih, lstm_b_hh, biasP);
    // zero c0,c1,hH0,hL0,hH1,hL1 (contiguous region)
    zero_range<<<2416, 256, 0, stream>>>(c0, 618496);

    // 5) chunked: feat split -> enhance MFMA -> Hcat split -> zin MFMA -> LSTM
    u16*   hHb[2] = {hH0, hH1};
    u16*   hLb[2] = {hL0, hL1};
    float* cb[2]  = {c0, c1};
    int cur = 0;
    for (int t0 = 0; t0 < Ndim; t0 += T) {
        int Mc = T * Bdim;
        split_rows8<<<dim3(2, Mc / 4), 256, 0, stream>>>(
            features, Edim, 255, Ndim, 8, 1, t0, FHc, FLc, Edim, Edim, Edim, Mc);
        gemm_mfma3<1,1><<<dim3(Mc/128, 8), 256, 0, stream>>>(
            FHc, FLc, Edim, EwH, EwL, Edim,
            nullptr, seqH, seqL, 1952, Mc, Edim, Edim, enhance_b, prelu_a);
        split_rows8<<<dim3(2, Mc / 4), 256, 0, stream>>>(
            Hcat, GDdim, 0x7FFFFFFF, 1, 30, 0, t0 * Bdim,
            seqH + 1024, seqL + 1024, 1952, 928, GDdim, Mc);
        gemm_mfma3<0,0><<<dim3(Mc/128, 19), 256, 0, stream>>>(
            seqH, seqL, 1952, WihPH, WihPL, 1952,
            zin, nullptr, nullptr, 4 * LHdim, Mc, 4 * LHdim, 1952, biasP, nullptr);
        for (int tl = 0; tl < T; ++tl) {
            lstm_mfma<<<dim3(8, 38), 256, 0, stream>>>(
                hHb[cur], hLb[cur], cb[cur], WhhPH, WhhPL,
                zin + (size_t)tl * Bdim * 4 * LHdim,
                hHb[cur ^ 1], hLb[cur ^ 1], cb[cur ^ 1],
                Hlstm + (size_t)(t0 + tl) * Bdim * LHdim);
            cur ^= 1;
        }
    }

    // 6) MLP head + output
    gemm_tn<1,0><<<dim3(ROWS/64, 5), 256, 0, stream>>>(
        Hlstm, LHdim, IDP, mlp_w0, LHdim, x1, HDdim, ROWS, HDdim, LHdim, mlp_b0, nullptr, mlp_a0);
    gemm_tn<1,0><<<dim3(ROWS/64, 5), 256, 0, stream>>>(
        x1, HDdim, IDP, mlp_w1, HDdim, x2, HDdim, ROWS, HDdim, HDdim, mlp_b1, nullptr, mlp_a1);
    out_kernel<<<ROWS / 4, 256, 0, stream>>>(x2, out_w, out_b, out);
}

// Round 9
// 4288.346 us; speedup vs baseline: 2.4722x; 1.0385x over previous
//
#include <hip/hip_runtime.h>
#include <cstdint>
#include <cstddef>

#define Bdim 256
#define Ndim 96
#define Edim 1024
#define HDdim 300
#define Ldim 2
#define LHdim 600
#define NCdim 7
#define GDdim 900              // HD*(L+1)
#define ROWS (Bdim*Ndim)       // 24576

typedef unsigned short u16;
typedef float f32x4 __attribute__((ext_vector_type(4)));
typedef short bf16x8 __attribute__((ext_vector_type(8)));

// Identity row-perm constants
#define IDP 0x7FFFFFFF, 1, 30, 0, 0

__device__ inline u16 f2bf(float x) {
    unsigned int u = __builtin_bit_cast(unsigned int, x);
    unsigned int r = (u + 0x7fffu + ((u >> 16) & 1u)) >> 16;   // RNE
    return (u16)r;
}
__device__ inline float bf2f(u16 h) {
    unsigned int u = ((unsigned int)h) << 16;
    return __builtin_bit_cast(float, u);
}

// ---------------------------------------------------------------------------
// bf16x3 split MFMA GEMM, bx-major bijective XCD swizzle (A-tile L2-resident
// per XCD, W panel streamed from L2/L3). reg->LDS staging (proven r4 path).
// C = act(sum_k (Ah+Al)[m,k]*(Wh+Wl)[n,k] + bias). K mult of 32; lda/ldw mult 8.
// W must have gridDim.y*128 rows allocated (pad rows zeroed).
// OUT: 0 -> fp32 C; 1 -> split bf16 (Ch,Cl). ACT: 1 -> prelu(aptr).
// Tile 128x128, BK=32, 4 waves (2x2), wave tile 64x64 = 4x4 frags of 16x16x32.
// ---------------------------------------------------------------------------
template<int OUT, int ACT>
__global__ __launch_bounds__(256) void gemm_mfma3(
    const u16* __restrict__ Ah, const u16* __restrict__ Al, int lda,
    const u16* __restrict__ Wh, const u16* __restrict__ Wl, int ldw,
    float* __restrict__ C, u16* __restrict__ Ch, u16* __restrict__ Cl, int ldc,
    int M, int Nd, int K,
    const float* __restrict__ bias, const float* __restrict__ aptr)
{
    __shared__ u16 AtH[4][1024];
    __shared__ u16 AtL[4][1024];
    __shared__ u16 WtH[4][1024];
    __shared__ u16 WtL[4][1024];
    const int tid  = threadIdx.x;
    // hw dispatch index (x-fastest); XCD = lin&7. Give each XCD a contiguous
    // chunk of bx-major work: A-tile stays hot while bn sweeps.
    const int ny  = gridDim.y;
    const int nwg = gridDim.x * ny;
    const int lin = blockIdx.y * gridDim.x + blockIdx.x;
    const int q = nwg >> 3, r8 = nwg & 7;
    const int xcd = lin & 7, off = lin >> 3;
    const int swz = (xcd < r8) ? xcd * (q + 1) + off
                               : r8 * (q + 1) + (xcd - r8) * q + off;
    const int bm   = (swz / ny) * 128;
    const int bn   = (swz % ny) * 128;
    const int wv   = tid >> 6;
    const int lane = tid & 63;
    const int wr   = (wv >> 1) * 64;
    const int wc   = (wv & 1) * 64;
    const int l15  = lane & 15;
    const int kseg = lane >> 4;

    f32x4 acc[4][4];
    #pragma unroll
    for (int i = 0; i < 4; ++i)
        #pragma unroll
        for (int j = 0; j < 4; ++j) acc[i][j] = (f32x4){0.f,0.f,0.f,0.f};

    const int srow = tid & 127;
    const bool isA = (tid < 128);
    const int gr   = isA ? (bm + srow) : (bn + srow);
    const int glim = isA ? M : 0x7FFFFFFF;            // W pad rows allocated+zeroed
    const u16* pHbase = (isA ? Ah : Wh) + (size_t)gr * (isA ? lda : ldw);
    const u16* pLbase = (isA ? Al : Wl) + (size_t)gr * (isA ? lda : ldw);
    u16* dH = isA ? &AtH[0][0] : &WtH[0][0];
    u16* dL = isA ? &AtL[0][0] : &WtL[0][0];

    for (int k0 = 0; k0 < K; k0 += 32) {
        __syncthreads();
        {
            const bool ok = (gr < glim);
            #pragma unroll
            for (int s = 0; s < 4; ++s) {
                bf16x8 vH = {0,0,0,0,0,0,0,0};
                bf16x8 vL = {0,0,0,0,0,0,0,0};
                if (ok) {
                    vH = *(const bf16x8*)(pHbase + k0 + s * 8);
                    vL = *(const bf16x8*)(pLbase + k0 + s * 8);
                }
                *(bf16x8*)(dH + s * 1024 + srow * 8) = vH;
                *(bf16x8*)(dL + s * 1024 + srow * 8) = vL;
            }
        }
        __syncthreads();
        bf16x8 aH[4], aL[4], bH[4], bL[4];
        #pragma unroll
        for (int f = 0; f < 4; ++f) {
            int ar = wr + f * 16 + l15;
            int br = wc + f * 16 + l15;
            aH[f] = *(const bf16x8*)&AtH[kseg][ar * 8];
            aL[f] = *(const bf16x8*)&AtL[kseg][ar * 8];
            bH[f] = *(const bf16x8*)&WtH[kseg][br * 8];
            bL[f] = *(const bf16x8*)&WtL[kseg][br * 8];
        }
        #pragma unroll
        for (int i = 0; i < 4; ++i)
            #pragma unroll
            for (int j = 0; j < 4; ++j)
                acc[i][j] = __builtin_amdgcn_mfma_f32_16x16x32_bf16(aH[i], bH[j], acc[i][j], 0, 0, 0);
        #pragma unroll
        for (int i = 0; i < 4; ++i)
            #pragma unroll
            for (int j = 0; j < 4; ++j)
                acc[i][j] = __builtin_amdgcn_mfma_f32_16x16x32_bf16(aH[i], bL[j], acc[i][j], 0, 0, 0);
        #pragma unroll
        for (int i = 0; i < 4; ++i)
            #pragma unroll
            for (int j = 0; j < 4; ++j)
                acc[i][j] = __builtin_amdgcn_mfma_f32_16x16x32_bf16(aL[i], bH[j], acc[i][j], 0, 0, 0);
    }

    const float av = (ACT == 1) ? *aptr : 0.f;
    const int r4 = (lane >> 4) * 4;
    #pragma unroll
    for (int j = 0; j < 4; ++j) {
        int col = bn + wc + j * 16 + l15;
        if (col >= Nd) continue;
        float bv = bias ? bias[col] : 0.f;
        #pragma unroll
        for (int i = 0; i < 4; ++i) {
            #pragma unroll
            for (int rr = 0; rr < 4; ++rr) {
                int row = bm + wr + i * 16 + r4 + rr;
                if (row >= M) continue;
                float v = acc[i][j][rr] + bv;
                if (ACT == 1) v = (v >= 0.f) ? v : av * v;
                if (OUT == 0) {
                    C[(size_t)row * ldc + col] = v;
                } else {
                    u16 h = f2bf(v);
                    Ch[(size_t)row * ldc + col] = h;
                    Cl[(size_t)row * ldc + col] = f2bf(v - bf2f(h));
                }
            }
        }
    }
}

// ---------------------------------------------------------------------------
// split fp32 -> bf16 hi/lo, vectorized: 4 rows/block, 8 cols/thread.
// rows (grid.y*4) and wcols (mult of 8) define the padded dst; src read only
// for r < validRows && c < validK, else zero-filled.
// ---------------------------------------------------------------------------
__global__ __launch_bounds__(256) void split_rows8(
    const float* __restrict__ src, int srcld,
    int pmask, int pmul1, int pshift, int pmul2, int padd,
    u16* __restrict__ dstH, u16* __restrict__ dstL, int dstld,
    int wcols, int validK, int validRows)
{
    const int r = blockIdx.y * 4 + (threadIdx.x >> 6);
    const int c = (blockIdx.x * 64 + (threadIdx.x & 63)) * 8;
    if (c >= wcols) return;
    const int sr = (r & pmask) * pmul1 + (r >> pshift) * pmul2 + padd;
    const float* s = src + (size_t)sr * srcld;
    const bool rok = (r < validRows);
    float v[8];
    if (rok && c + 8 <= validK) {
        *(float4*)&v[0] = *(const float4*)(s + c);
        *(float4*)&v[4] = *(const float4*)(s + c + 4);
    } else {
        #pragma unroll
        for (int u = 0; u < 8; ++u) v[u] = (rok && c + u < validK) ? s[c + u] : 0.f;
    }
    bf16x8 H8, L8;
    #pragma unroll
    for (int u = 0; u < 8; ++u) {
        u16 h = f2bf(v[u]);
        H8[u] = (short)h;
        L8[u] = (short)f2bf(v[u] - bf2f(h));
    }
    *(bf16x8*)(dstH + (size_t)r * dstld + c) = H8;
    *(bf16x8*)(dstL + (size_t)r * dstld + c) = L8;
}

// biasP[n'] = b_ih[orig]+b_hh[orig], orig = (n'&3)*600+(n'>>2)
__global__ __launch_bounds__(256) void bias_perm(
    const float* __restrict__ bih, const float* __restrict__ bhh, float* __restrict__ dst)
{
    int n = blockIdx.x * 256 + threadIdx.x;
    if (n >= 4 * LHdim) return;
    int o = (n & 3) * LHdim + (n >> 2);
    dst[n] = bih[o] + bhh[o];
}

// Wr2f[l][r][c]: r<300 -> wr0[l][r][c], else wr1[l][r-300][c]
__global__ __launch_bounds__(256) void wr_cat(
    const float* __restrict__ wr0, const float* __restrict__ wr1, float* __restrict__ dst)
{
    int c = blockIdx.x * 256 + threadIdx.x;
    if (c >= HDdim) return;
    int lr = blockIdx.y;
    int l = lr / (2 * HDdim), r = lr % (2 * HDdim);
    const float* src = (r < HDdim)
        ? wr0 + ((size_t)l * HDdim + r) * HDdim
        : wr1 + ((size_t)l * HDdim + (r - HDdim)) * HDdim;
    dst[(size_t)lr * HDdim + c] = src[c];
}

__global__ __launch_bounds__(256) void zero_range(float* __restrict__ p, int n)
{
    int i = blockIdx.x * 256 + threadIdx.x;
    if (i < n) p[i] = 0.f;
}

// ---------------------------------------------------------------------------
__global__ __launch_bounds__(256) void norm_kernel(const float* __restrict__ f, float* __restrict__ invn)
{
    int row  = blockIdx.x * 4 + (threadIdx.x >> 6);
    int lane = threadIdx.x & 63;
    const float* fr = f + (size_t)row * Edim;
    float ss = 0.f;
    for (int t = lane; t < Edim; t += 64) { float v = fr[t]; ss = fmaf(v, v, ss); }
    #pragma unroll
    for (int o = 32; o > 0; o >>= 1) ss += __shfl_down(ss, o);
    if (lane == 0) invn[row] = 1.f / (sqrtf(ss) + 1e-8f);
}

__global__ __launch_bounds__(256) void simadj_kernel(
    const float* __restrict__ f, const float* __restrict__ invn,
    const float* __restrict__ entro, const float* __restrict__ alphap,
    const float* __restrict__ thrp, uint8_t* __restrict__ adj)
{
    int b = blockIdx.x;
    __shared__ float S[16][100];
    int tid = threadIdx.x;
    int i0 = (tid >> 4) * 6, j0 = (tid & 15) * 6;
    float acc[6][6];
    #pragma unroll
    for (int i = 0; i < 6; ++i)
        #pragma unroll
        for (int j = 0; j < 6; ++j) acc[i][j] = 0.f;
    const float* fb = f + (size_t)b * Ndim * Edim;

    for (int k0 = 0; k0 < Edim; k0 += 16) {
        __syncthreads();
        #pragma unroll
        for (int r = 0; r < 6; ++r) {
            int n = (tid >> 4) + r * 16;
            S[tid & 15][n] = fb[(size_t)n * Edim + k0 + (tid & 15)];
        }
        __syncthreads();
        #pragma unroll
        for (int kk = 0; kk < 16; ++kk) {
            float a[6], bb[6];
            #pragma unroll
            for (int u = 0; u < 6; ++u) a[u] = S[kk][i0 + u];
            #pragma unroll
            for (int u = 0; u < 6; ++u) bb[u] = S[kk][j0 + u];
            #pragma unroll
            for (int i = 0; i < 6; ++i)
                #pragma unroll
                for (int j = 0; j < 6; ++j)
                    acc[i][j] = fmaf(a[i], bb[j], acc[i][j]);
        }
    }

    float alpha = *alphap, thr = *thrp;
    float onem = 1.f - alpha;
    #pragma unroll
    for (int i = 0; i < 6; ++i) {
        int ii = i0 + i;
        float inv_i = invn[b * Ndim + ii];
        #pragma unroll
        for (int j = 0; j < 6; ++j) {
            int jj = j0 + j;
            float simv = acc[i][j] * inv_i * invn[b * Ndim + jj];
            float comb = alpha * entro[b * Ndim + jj] + onem * simv;
            adj[((size_t)b * Ndim + ii) * Ndim + jj] = (comb > thr) ? 1 : 0;
        }
    }
}

__global__ __launch_bounds__(256) void qk_kernel(
    const float* __restrict__ Hsrc, const float* __restrict__ wqk,
    float* __restrict__ q, float* __restrict__ k)
{
    int row  = blockIdx.x * 4 + (threadIdx.x >> 6);
    int lane = threadIdx.x & 63;
    const float* h = Hsrc + (size_t)row * GDdim;
    float sq = 0.f, sk = 0.f;
    for (int t = lane; t < HDdim; t += 64) {
        float hv = h[t];
        sq = fmaf(hv, wqk[t], sq);
        sk = fmaf(hv, wqk[HDdim + t], sk);
    }
    #pragma unroll
    for (int o = 32; o > 0; o >>= 1) { sq += __shfl_down(sq, o); sk += __shfl_down(sk, o); }
    if (lane == 0) { q[row] = sq; k[row] = sk; }
}

// ---------------------------------------------------------------------------
// Fused GAT attention for one batch b (q, gat_b cancel in softmax).
// V combined: cols 0..299 = V0, 300..599 = V1, row stride 600 (n-major rows).
// ---------------------------------------------------------------------------
__global__ __launch_bounds__(256) void gat_fused(
    const float* __restrict__ kbuf, const uint8_t* __restrict__ adj,
    const int* __restrict__ smask,
    const float* __restrict__ V,
    float* __restrict__ Mout)
{
    __shared__ float P0[96][98];
    __shared__ float P1[96][98];
    __shared__ float Vs0[96][96];
    __shared__ float Vs1[96][96];
    __shared__ float ek[96];
    __shared__ float rden[96];
    __shared__ float red[256];
    const int b = blockIdx.x;
    const int tid = threadIdx.x;

    float kj = (tid < Ndim) ? kbuf[tid * Bdim + b] : -1e30f;
    red[tid] = kj;
    __syncthreads();
    #pragma unroll
    for (int s = 128; s > 0; s >>= 1) {
        if (tid < s) red[tid] = fmaxf(red[tid], red[tid + s]);
        __syncthreads();
    }
    float kmax = red[0];
    if (tid < Ndim) ek[tid] = expf(kj - kmax);
    __syncthreads();
    if (tid < Ndim) {
        const uint8_t* ar = adj + ((size_t)b * Ndim + tid) * Ndim;
        float s = 0.f;
        for (int j = 0; j < Ndim; ++j) if (ar[j]) s += ek[j];
        rden[tid] = 1.f / s;   // diagonal always allowed -> s > 0
    }
    __syncthreads();
    for (int idx = tid; idx < Ndim * Ndim; idx += 256) {
        int i = idx / Ndim, j = idx - i * Ndim;
        float a = adj[((size_t)b * Ndim + i) * Ndim + j] ? ek[j] * rden[i] : 0.f;
        int s = smask[((size_t)b * Ndim + i) * Ndim + j];
        P0[i][j] = s ? a : 0.f;
        P1[i][j] = s ? 0.f : a;
    }
    __syncthreads();

    const int ti = tid >> 4, td = tid & 15;
    const int i0 = ti * 6, dbase = td * 6;
    for (int p = 0; p < 4; ++p) {
        const int d0 = p * 96;
        const int dw = (p == 3) ? (HDdim - 288) : 96;
        for (int idx = tid; idx < 96 * 24; idx += 256) {
            int j = idx / 24, q4 = (idx - j * 24) * 4;
            if (q4 < dw) {
                size_t g = ((size_t)(j * Bdim + b)) * (2 * HDdim) + d0 + q4;
                *(float4*)&Vs0[j][q4] = *(const float4*)(V + g);
                *(float4*)&Vs1[j][q4] = *(const float4*)(V + g + HDdim);
            }
        }
        __syncthreads();
        float acc[6][6];
        #pragma unroll
        for (int ii = 0; ii < 6; ++ii)
            #pragma unroll
            for (int dd = 0; dd < 6; ++dd) acc[ii][dd] = 0.f;
        for (int j = 0; j < Ndim; j += 2) {
            float2 pa[6], pb[6];
            #pragma unroll
            for (int ii = 0; ii < 6; ++ii) {
                pa[ii] = *(const float2*)&P0[i0 + ii][j];
                pb[ii] = *(const float2*)&P1[i0 + ii][j];
            }
            float2 v0a[3], v0b[3], v1a[3], v1b[3];
            #pragma unroll
            for (int dd = 0; dd < 3; ++dd) {
                v0a[dd] = *(const float2*)&Vs0[j][dbase + 2 * dd];
                v0b[dd] = *(const float2*)&Vs0[j + 1][dbase + 2 * dd];
                v1a[dd] = *(const float2*)&Vs1[j][dbase + 2 * dd];
                v1b[dd] = *(const float2*)&Vs1[j + 1][dbase + 2 * dd];
            }
            #pragma unroll
            for (int ii = 0; ii < 6; ++ii)
                #pragma unroll
                for (int dd = 0; dd < 3; ++dd) {
                    acc[ii][2*dd]   += pa[ii].x * v0a[dd].x + pb[ii].x * v1a[dd].x
                                     + pa[ii].y * v0b[dd].x + pb[ii].y * v1b[dd].x;
                    acc[ii][2*dd+1] += pa[ii].x * v0a[dd].y + pb[ii].x * v1a[dd].y
                                     + pa[ii].y * v0b[dd].y + pb[ii].y * v1b[dd].y;
                }
        }
        __syncthreads();
        #pragma unroll
        for (int ii = 0; ii < 6; ++ii) {
            #pragma unroll
            for (int dd = 0; dd < 6; ++dd) {
                int d = dbase + dd;
                if (d < dw)
                    Mout[((size_t)((i0 + ii) * Bdim + b)) * GDdim + d0 + d] = acc[ii][dd];
            }
        }
    }
}

// ---------------------------------------------------------------------------
// LSTM step via bf16x3 MFMA. h split-bf16 (256 x 608, pads zero).
// W = WhhP split bf16 (2432 x 608, gate-interleaved rows, pads zero).
// Tile 32 batch x 64 gate-cols, grid (8,38). Writes recurrence h (split),
// c (fp32) and the sequence output Hl as split bf16 (stride 608).
// ---------------------------------------------------------------------------
__global__ __launch_bounds__(256) void lstm_mfma(
    const u16* __restrict__ hH, const u16* __restrict__ hL,
    const float* __restrict__ cin,
    const u16* __restrict__ WH, const u16* __restrict__ WL,
    const float* __restrict__ zt,
    u16* __restrict__ hHo, u16* __restrict__ hLo,
    float* __restrict__ cout,
    u16* __restrict__ HlH, u16* __restrict__ HlL)
{
    __shared__ u16 AsH[4][256];
    __shared__ u16 AsL[4][256];
    __shared__ u16 WsH[4][512];
    __shared__ u16 WsL[4][512];
    __shared__ __align__(16) float gates[32][68];
    const int tid = threadIdx.x;
    const int bm = blockIdx.x * 32;
    const int bn = blockIdx.y * 64;
    const int wv = tid >> 6;
    const int lane = tid & 63;
    const int l15 = lane & 15;
    const int kseg = lane >> 4;

    const int av = tid & 127;
    const int arow = av >> 2, akc = av & 3;
    const u16* asrc = ((tid < 128) ? hH : hL) + (size_t)(bm + arow) * 608 + akc * 8;
    u16* adst = ((tid < 128) ? &AsH[0][0] : &AsL[0][0]) + akc * 256 + arow * 8;
    const int wrow = tid >> 2, wkc = tid & 3;
    const u16* wsrcH = WH + (size_t)(bn + wrow) * 608 + wkc * 8;
    const u16* wsrcL = WL + (size_t)(bn + wrow) * 608 + wkc * 8;
    u16* wdstH = &WsH[wkc][wrow * 8];
    u16* wdstL = &WsL[wkc][wrow * 8];

    f32x4 acc[2];
    acc[0] = (f32x4){0.f,0.f,0.f,0.f};
    acc[1] = (f32x4){0.f,0.f,0.f,0.f};

    for (int k0 = 0; k0 < 608; k0 += 32) {
        __syncthreads();
        *(bf16x8*)adst  = *(const bf16x8*)(asrc + k0);
        *(bf16x8*)wdstH = *(const bf16x8*)(wsrcH + k0);
        *(bf16x8*)wdstL = *(const bf16x8*)(wsrcL + k0);
        __syncthreads();
        bf16x8 aH[2], aL[2], bH, bL;
        #pragma unroll
        for (int i = 0; i < 2; ++i) {
            int ar = i * 16 + l15;
            aH[i] = *(const bf16x8*)&AsH[kseg][ar * 8];
            aL[i] = *(const bf16x8*)&AsL[kseg][ar * 8];
        }
        {
            int br = wv * 16 + l15;
            bH = *(const bf16x8*)&WsH[kseg][br * 8];
            bL = *(const bf16x8*)&WsL[kseg][br * 8];
        }
        #pragma unroll
        for (int i = 0; i < 2; ++i) {
            acc[i] = __builtin_amdgcn_mfma_f32_16x16x32_bf16(aH[i], bH, acc[i], 0, 0, 0);
            acc[i] = __builtin_amdgcn_mfma_f32_16x16x32_bf16(aH[i], bL, acc[i], 0, 0, 0);
            acc[i] = __builtin_amdgcn_mfma_f32_16x16x32_bf16(aL[i], bH, acc[i], 0, 0, 0);
        }
    }

    const int r4 = (lane >> 4) * 4;
    __syncthreads();
    #pragma unroll
    for (int i = 0; i < 2; ++i)
        #pragma unroll
        for (int rr = 0; rr < 4; ++rr)
            gates[i * 16 + r4 + rr][wv * 16 + l15] = acc[i][rr];
    __syncthreads();

    #pragma unroll
    for (int s = 0; s < 2; ++s) {
        int cell = tid + s * 256;
        int row = cell >> 4;
        int ui  = cell & 15;
        int n0  = bn + ui * 4;
        int u   = n0 >> 2;
        if (u < LHdim) {
            int bb = bm + row;
            float4 g = *(const float4*)&gates[row][ui * 4];
            const float* z = zt + (size_t)bb * (4 * LHdim) + n0;
            float gi = g.x + z[0];
            float gf = g.y + z[1];
            float gg = g.z + z[2];
            float go = g.w + z[3];
            float si = 1.f / (1.f + expf(-gi));
            float sf = 1.f / (1.f + expf(-gf));
            float so = 1.f / (1.f + expf(-go));
            float cn = sf * cin[bb * LHdim + u] + si * tanhf(gg);
            float hn = so * tanhf(cn);
            cout[bb * LHdim + u] = cn;
            u16 hh = f2bf(hn);
            u16 hl = f2bf(hn - bf2f(hh));
            hHo[(size_t)bb * 608 + u] = hh;
            hLo[(size_t)bb * 608 + u] = hl;
            HlH[(size_t)bb * 608 + u] = hh;
            HlL[(size_t)bb * 608 + u] = hl;
        }
    }
}

__global__ __launch_bounds__(256) void out_kernel(
    const float* __restrict__ x, int ldx, const float* __restrict__ ow,
    const float* __restrict__ ob, float* __restrict__ out)
{
    int r    = blockIdx.x * 4 + (threadIdx.x >> 6);
    int lane = threadIdx.x & 63;
    const float* xr = x + (size_t)r * ldx;
    float acc[NCdim];
    #pragma unroll
    for (int n = 0; n < NCdim; ++n) acc[n] = 0.f;
    for (int t = lane; t < HDdim; t += 64) {
        float xv = xr[t];
        #pragma unroll
        for (int n = 0; n < NCdim; ++n) acc[n] = fmaf(xv, ow[n * HDdim + t], acc[n]);
    }
    #pragma unroll
    for (int o = 32; o > 0; o >>= 1)
        #pragma unroll
        for (int n = 0; n < NCdim; ++n) acc[n] += __shfl_down(acc[n], o);
    if (lane == 0) {
        int b = r & 255, nn = r >> 8;
        #pragma unroll
        for (int n = 0; n < NCdim; ++n) out[((size_t)b * Ndim + nn) * NCdim + n] = acc[n] + ob[n];
    }
}

// ---------------------------------------------------------------------------
extern "C" void kernel_launch(void* const* d_in, const int* in_sizes, int n_in,
                              void* d_out, int out_size, void* d_ws, size_t ws_size,
                              hipStream_t stream)
{
    const float*  features  = (const float*)d_in[0];
    const int*    s_mask    = (const int*)  d_in[1];
    const float*  entro     = (const float*)d_in[2];
    const float*  alpha     = (const float*)d_in[3];
    const float*  threshold = (const float*)d_in[4];
    const float*  fc1_w     = (const float*)d_in[5];
    const float*  fc1_b     = (const float*)d_in[6];
    const float*  gat_w     = (const float*)d_in[7];
    const float*  gat_b     = (const float*)d_in[8];
    const float*  wr0       = (const float*)d_in[9];
    const float*  wr1       = (const float*)d_in[10];
    const float*  enhance_w = (const float*)d_in[11];
    const float*  enhance_b = (const float*)d_in[12];
    const float*  prelu_a   = (const float*)d_in[13];
    const float*  lstm_w_ih = (const float*)d_in[14];
    const float*  lstm_w_hh = (const float*)d_in[15];
    const float*  lstm_b_ih = (const float*)d_in[16];
    const float*  lstm_b_hh = (const float*)d_in[17];
    const float*  mlp_w0    = (const float*)d_in[18];
    const float*  mlp_b0    = (const float*)d_in[19];
    const float*  mlp_a0    = (const float*)d_in[20];
    const float*  mlp_w1    = (const float*)d_in[21];
    const float*  mlp_b1    = (const float*)d_in[22];
    const float*  mlp_a1    = (const float*)d_in[23];
    const float*  out_w     = (const float*)d_in[24];
    const float*  out_b     = (const float*)d_in[25];
    float* out = (float*)d_out;
    char* ws = (char*)d_ws;

    // ---- fixed workspace layout (bytes, 256-aligned) ----
    uint8_t* adj   = (uint8_t*)(ws + 0);               //  2,359,296
    float*   invn  = (float*)(ws + 2359296);
    float*   qbuf  = (float*)(ws + 2457600);
    float*   kbuf  = (float*)(ws + 2555904);
    float*   biasP = (float*)(ws + 2654208);
    float*   c0    = (float*)(ws + 2663936);           //    614,400
    float*   c1    = (float*)(ws + 3278336);
    u16*     hH0   = (u16*)(ws + 3892736);             //    311,296 (256 x 608)
    u16*     hL0   = (u16*)(ws + 4204032);
    u16*     hH1   = (u16*)(ws + 4515328);
    u16*     hL1   = (u16*)(ws + 4826624);
    u16*     WhhPH = (u16*)(ws + 5137920);             //  2,957,312 (2432 x 608)
    u16*     WhhPL = (u16*)(ws + 8095232);
    u16*     WihPH = (u16*)(ws + 11052544);            //  9,494,528 (2432 x 1952)
    u16*     WihPL = (u16*)(ws + 20547072);
    u16*     EwH   = (u16*)(ws + 30041600);            //  2,097,152 (1024 x 1024)
    u16*     EwL   = (u16*)(ws + 32138752);
    u16*     Fc1H  = (u16*)(ws + 34235904);            //    786,432 (384 x 1024)
    u16*     Fc1L  = (u16*)(ws + 35022336);
    float*   Wr2f  = (float*)(ws + 35808768);          //  1,440,256 (2 x 600 x 300)
    u16*     Wr2H  = (u16*)(ws + 37249024);            //    819,200 (2 x 640 x 320)
    u16*     Wr2L  = (u16*)(ws + 38068224);
    u16*     Wm0H  = (u16*)(ws + 38887424);            //    524,288 (384 x 608)
    u16*     Wm0L  = (u16*)(ws + 39411712);
    u16*     Wm1H  = (u16*)(ws + 39936000);            //    262,144 (384 x 320)
    u16*     Wm1L  = (u16*)(ws + 40198144);
    u16*     FfH   = (u16*)(ws + 40460288);            // 50,331,648 (ROWS x 1024)
    u16*     FfL   = (u16*)(ws + 90791936);
    float*   Hcat  = (float*)(ws + 141123584);         // 88,473,600 (ROWS,900) n-major
    u16*     HsH   = (u16*)(ws + 229597184);           // 15,728,640 (ROWS x 320)
    u16*     HsL   = (u16*)(ws + 245325824);
    // V (GAT, fp32 ROWSx600) aliases HlstmH/L (split ROWSx608) — phase-disjoint
    float*   V      = (float*)(ws + 261054464);        // 58,982,400
    u16*     HlstmH = (u16*)(ws + 261054464);          // 29,884,416
    u16*     HlstmL = (u16*)(ws + 290938880);          // 29,884,416 -> 320,823,296
    // MLP scratch aliases Hcat (dead after last Hcat split)
    u16*     x1H   = (u16*)Hcat;                       // 15,728,640 (ROWS x 320)
    u16*     x1L   = (u16*)(ws + 141123584 + 15728640);
    float*   x2    = (float*)(ws + 141123584 + 31457280);   // 29,884,416 (ROWS x 304)

    // ---- tier selection for chunked seq/zin region ----
    const size_t fixedNeed = 320823296ull;
    const size_t perT = 4456448ull;                    // zin(2,457,600)+seqH/L(1,998,848)
    int T;
    if      (ws_size >= fixedNeed + 96ull * perT) T = 96;
    else if (ws_size >= fixedNeed + 48ull * perT) T = 48;
    else if (ws_size >= fixedNeed + 32ull * perT) T = 32;
    else if (ws_size >= fixedNeed + 16ull * perT) T = 16;
    else if (ws_size >= fixedNeed +  8ull * perT) T = 8;
    else return;                                       // visible failure, no OOB
    char* cr = ws + fixedNeed;
    float* zin  = (float*)cr;                                // (Mc,2400)
    u16*   seqH = (u16*)(cr + (size_t)T * 2457600);          // (Mc,1952)
    u16*   seqL = (u16*)(cr + (size_t)T * 2457600 + (size_t)T * 999424);

    // 1) norms + adjacency
    norm_kernel<<<ROWS / 4, 256, 0, stream>>>(features, invn);
    simadj_kernel<<<Bdim, 256, 0, stream>>>(features, invn, entro, alpha, threshold, adj);

    // 2) weight/activation conversions
    split_rows8<<<dim3(2, ROWS / 4), 256, 0, stream>>>(            // features n-major full
        features, Edim, 255, Ndim, 8, 1, 0, FfH, FfL, Edim, Edim, Edim, ROWS);
    split_rows8<<<dim3(2, 96), 256, 0, stream>>>(                  // fc1_w (384x1024)
        fc1_w, Edim, IDP, Fc1H, Fc1L, Edim, Edim, Edim, HDdim);
    split_rows8<<<dim3(2, 256), 256, 0, stream>>>(                 // enhance_w
        enhance_w, Edim, IDP, EwH, EwL, Edim, Edim, Edim, Edim);
    split_rows8<<<dim3(4, 608), 256, 0, stream>>>(                 // Wih gate-interleaved
        lstm_w_ih, Edim + GDdim, 3, LHdim, 2, 1, 0, WihPH, WihPL, 1952, 1952, 1924, 2400);
    split_rows8<<<dim3(2, 608), 256, 0, stream>>>(                 // Whh gate-interleaved
        lstm_w_hh, LHdim, 3, LHdim, 2, 1, 0, WhhPH, WhhPL, 608, 608, LHdim, 2400);
    split_rows8<<<dim3(2, 96), 256, 0, stream>>>(                  // mlp_w0 (384x608)
        mlp_w0, LHdim, IDP, Wm0H, Wm0L, 608, 608, LHdim, HDdim);
    split_rows8<<<dim3(1, 96), 256, 0, stream>>>(                  // mlp_w1 (384x320)
        mlp_w1, HDdim, IDP, Wm1H, Wm1L, 320, 320, HDdim, HDdim);
    wr_cat<<<dim3(2, 2 * Ldim * HDdim), 256, 0, stream>>>(wr0, wr1, Wr2f);
    for (int l = 0; l < Ldim; ++l)
        split_rows8<<<dim3(1, 160), 256, 0, stream>>>(             // Wr2 (640x320 per layer)
            Wr2f + (size_t)l * 2 * HDdim * HDdim, HDdim, IDP,
            Wr2H + (size_t)l * 640 * 320, Wr2L + (size_t)l * 640 * 320,
            320, 320, HDdim, 2 * HDdim);
    bias_perm<<<10, 256, 0, stream>>>(lstm_b_ih, lstm_b_hh, biasP);
    zero_range<<<2416, 256, 0, stream>>>(c0, 618496);              // c0,c1,h buffers

    // 3) H0 = prelu(features @ fc1_w^T + fc1_b) -> Hcat[:, 0:300] (MFMA)
    gemm_mfma3<0,1><<<dim3(ROWS/128, 3), 256, 0, stream>>>(
        FfH, FfL, Edim, Fc1H, Fc1L, Edim,
        Hcat, nullptr, nullptr, GDdim, ROWS, HDdim, Edim, fc1_b, prelu_a);

    // 4) GAT layers (MFMA V projection, fused softmax+aggregation)
    for (int l = 0; l < Ldim; ++l) {
        const float* Hsrc = Hcat + l * HDdim;
        qk_kernel<<<ROWS / 4, 256, 0, stream>>>(Hsrc, gat_w + l * 2 * HDdim, qbuf, kbuf);
        split_rows8<<<dim3(1, ROWS / 4), 256, 0, stream>>>(        // Hsrc -> split (K=320)
            Hsrc, GDdim, IDP, HsH, HsL, 320, 320, HDdim, ROWS);
        gemm_mfma3<0,0><<<dim3(ROWS/128, 5), 256, 0, stream>>>(
            HsH, HsL, 320, Wr2H + (size_t)l * 640 * 320, Wr2L + (size_t)l * 640 * 320, 320,
            V, nullptr, nullptr, 2 * HDdim, ROWS, 2 * HDdim, 320, nullptr, nullptr);
        gat_fused<<<Bdim, 256, 0, stream>>>(
            kbuf, adj, s_mask, V, Hcat + (l + 1) * HDdim);
    }

    // 5) zero Hlstm split region (pads must be 0; region aliased V until now)
    zero_range<<<58368, 256, 0, stream>>>((float*)HlstmH, 14942208);

    // 6) chunked: enhance MFMA -> Hcat split -> zin MFMA -> LSTM steps
    u16*   hHb[2] = {hH0, hH1};
    u16*   hLb[2] = {hL0, hL1};
    float* cb[2]  = {c0, c1};
    int cur = 0;
    for (int t0 = 0; t0 < Ndim; t0 += T) {
        int Mc = T * Bdim;
        gemm_mfma3<1,1><<<dim3(Mc/128, 8), 256, 0, stream>>>(
            FfH + (size_t)t0 * Bdim * Edim, FfL + (size_t)t0 * Bdim * Edim, Edim,
            EwH, EwL, Edim,
            nullptr, seqH, seqL, 1952, Mc, Edim, Edim, enhance_b, prelu_a);
        split_rows8<<<dim3(2, Mc / 4), 256, 0, stream>>>(
            Hcat, GDdim, 0x7FFFFFFF, 1, 30, 0, t0 * Bdim,
            seqH + 1024, seqL + 1024, 1952, 928, GDdim, Mc);
        gemm_mfma3<0,0><<<dim3(Mc/128, 19), 256, 0, stream>>>(
            seqH, seqL, 1952, WihPH, WihPL, 1952,
            zin, nullptr, nullptr, 4 * LHdim, Mc, 4 * LHdim, 1952, biasP, nullptr);
        for (int tl = 0; tl < T; ++tl) {
            lstm_mfma<<<dim3(8, 38), 256, 0, stream>>>(
                hHb[cur], hLb[cur], cb[cur], WhhPH, WhhPL,
                zin + (size_t)tl * Bdim * 4 * LHdim,
                hHb[cur ^ 1], hLb[cur ^ 1], cb[cur ^ 1],
                HlstmH + (size_t)(t0 + tl) * Bdim * 608,
                HlstmL + (size_t)(t0 + tl) * Bdim * 608);
            cur ^= 1;
        }
    }

    // 7) MLP head (MFMA) + output
    zero_range<<<30720, 256, 0, stream>>>((float*)x1H, 7864320);   // x1 pads must be 0
    gemm_mfma3<1,1><<<dim3(ROWS/128, 3), 256, 0, stream>>>(
        HlstmH, HlstmL, 608, Wm0H, Wm0L, 608,
        nullptr, x1H, x1L, 320, ROWS, HDdim, 608, mlp_b0, mlp_a0);
    gemm_mfma3<0,1><<<dim3(ROWS/128, 3), 256, 0, stream>>>(
        x1H, x1L, 320, Wm1H, Wm1L, 320,
        x2, nullptr, nullptr, 304, ROWS, HDdim, 320, mlp_b1, mlp_a1);
    out_kernel<<<ROWS / 4, 256, 0, stream>>>(x2, 304, out_w, out_b, out);
}